// Round 1
// baseline (4046.530 us; speedup 1.0000x reference)
//
#include <hip/hip_runtime.h>
#include <math.h>

#define NEG_INF (-1e9f)

// ---------------------------------------------------------------------------
// pre_kernel: builds into ws
//   ws[0 .. 16383]   : Wc[e][d] = (1/sqrt(128)) * sum_j W_node[e,256+j]*W_out[d,j]
//   ws[16384..16511] : qp[d]    = sum_i W_placeholder[i]*W_step[i,d]
// ---------------------------------------------------------------------------
__global__ __launch_bounds__(128) void pre_kernel(
    const float* __restrict__ W_node, const float* __restrict__ W_out,
    const float* __restrict__ W_step, const float* __restrict__ W_ph,
    float* __restrict__ ws) {
  const int bi = blockIdx.x;
  const int tid = threadIdx.x;
  if (bi < 64) {
    __shared__ float woT[64][133];  // transposed W_out chunk, padded stride 133
    float acc0 = 0.f, acc1 = 0.f;
    const int e0 = bi * 2, e1 = e0 + 1;
    for (int ch = 0; ch < 2; ++ch) {
      const int j0 = ch * 64;
      for (int it = 0; it < 64; ++it) {
        int idx = tid + it * 128;           // 0..8191
        int jj = idx & 63, ds = idx >> 6;   // coalesced global read
        woT[jj][ds] = W_out[ds * 128 + j0 + jj];
      }
      __syncthreads();
      for (int jj = 0; jj < 64; ++jj) {
        int j = j0 + jj;
        float a0 = W_node[e0 * 384 + 256 + j];
        float a1 = W_node[e1 * 384 + 256 + j];
        float bb = woT[jj][tid];            // conflict-free (pad 133)
        acc0 = fmaf(a0, bb, acc0);
        acc1 = fmaf(a1, bb, acc1);
      }
      __syncthreads();
    }
    const float rs = 0.08838834764831845f;  // 1/sqrt(128)
    ws[e0 * 128 + tid] = acc0 * rs;
    ws[e1 * 128 + tid] = acc1 * rs;
  } else {
    float acc = 0.f;
    for (int i = 0; i < 256; ++i) acc = fmaf(W_ph[i], W_step[i * 128 + tid], acc);
    ws[16384 + tid] = acc;
  }
}

// ---------------------------------------------------------------------------
// decode_kernel: one block per batch row; 512 threads; loops t=0..99.
// Thread (c = tid&31, g = tid>>5): owns col-quad d=4c..4c+3 of rows n=g+16k.
// gk/gv/lk' register-resident (84 VGPRs). E = emb@W_step_bot in LDS
// (overwrites the emb staging area). 0.25 (1/sqrt(dk)) folded into query
// components; 1/sqrt(128) folded into Wc by pre_kernel.
// ---------------------------------------------------------------------------
__global__ __launch_bounds__(512) void decode_kernel(
    const float* __restrict__ emb,      // [2048][100][128]
    const float* __restrict__ W_node,   // [128][384]
    const float* __restrict__ W_fixed,  // [128][128]
    const float* __restrict__ W_step,   // [256][128]
    const float* __restrict__ ws,       // Wc + qp
    float* __restrict__ out_logp,       // [2048][100][100]
    float* __restrict__ out_pi) {       // [2048][100] (as float)
  const int b = blockIdx.x;
  const int tid = threadIdx.x;
  const int c = tid & 31;
  const int g = tid >> 5;   // 0..15
  const int h = c >> 2;     // head
  const int lane = tid & 63;
  const int wave = tid >> 6;  // 0..7

  __shared__ __align__(16) float semb[100][128];  // emb staging -> later E
  __shared__ __align__(16) float scomp[8][100];   // compat / attn
  __shared__ float slog[100];
  __shared__ __align__(16) float red[8][32][4];
  __shared__ float smean[128];
  __shared__ float sf[4];
  __shared__ int si[4];

  const float* embB = emb + (size_t)b * 12800;

  // ---- stage emb into LDS (coalesced float4) ----
  for (int it = 0; it < 7; ++it) {
    int qi = tid + it * 512;
    if (qi < 3200) ((float4*)&semb[0][0])[qi] = ((const float4*)embB)[qi];
  }
  __syncthreads();

  // ---- graph mean ----
  {
    int d = tid & 127, q = tid >> 7;
    float p = 0.f;
    for (int n = q * 25; n < q * 25 + 25; ++n) p += semb[n][d];
    ((float*)red)[q * 128 + d] = p;
  }
  __syncthreads();
  if (tid < 128) {
    float* rf = (float*)red;
    smean[tid] = (rf[tid] + rf[128 + tid] + rf[256 + tid] + rf[384 + tid]) / 100.0f;
  }
  __syncthreads();

  // ---- fixed_context quad (x0.25 folded) ----
  float4 ctx4;
  {
    float ax = 0.f, ay = 0.f, az = 0.f, aw = 0.f;
    for (int i = 0; i < 8; ++i) {
      int dd = g * 8 + i;
      float mv = smean[dd];
      float4 wq = *(const float4*)(W_fixed + dd * 128 + 4 * c);
      ax = fmaf(mv, wq.x, ax); ay = fmaf(mv, wq.y, ay);
      az = fmaf(mv, wq.z, az); aw = fmaf(mv, wq.w, aw);
    }
    ax += __shfl_xor(ax, 32); ay += __shfl_xor(ay, 32);
    az += __shfl_xor(az, 32); aw += __shfl_xor(aw, 32);
    if (lane < 32) { red[wave][c][0] = ax; red[wave][c][1] = ay; red[wave][c][2] = az; red[wave][c][3] = aw; }
    __syncthreads();
    float sx = 0.f, sy = 0.f, sz = 0.f, sw = 0.f;
    for (int ww = 0; ww < 8; ++ww) {
      sx += red[ww][c][0]; sy += red[ww][c][1]; sz += red[ww][c][2]; sw += red[ww][c][3];
    }
    ctx4.x = 0.25f * sx; ctx4.y = 0.25f * sy; ctx4.z = 0.25f * sz; ctx4.w = 0.25f * sw;
    __syncthreads();
  }

  // ---- qp quad (x0.25 folded) ----
  float4 qp4 = *(const float4*)(ws + 16384 + 4 * c);
  qp4.x *= 0.25f; qp4.y *= 0.25f; qp4.z *= 0.25f; qp4.w *= 0.25f;

  // ---- gk / gv / lk' into registers ----
  float4 gk_r[7], gv_r[7], lk_r[7];
#pragma unroll
  for (int k = 0; k < 7; ++k) {
    gk_r[k] = make_float4(0, 0, 0, 0);
    gv_r[k] = make_float4(0, 0, 0, 0);
    lk_r[k] = make_float4(0, 0, 0, 0);
  }
  const float* Wc = ws;
#pragma unroll 2
  for (int e4 = 0; e4 < 32; ++e4) {
    float4 em[7];
#pragma unroll
    for (int k = 0; k < 7; ++k) {
      int n = g + 16 * k; n = (n < 100) ? n : 99;
      em[k] = *(const float4*)(&semb[n][e4 * 4]);
    }
#pragma unroll
    for (int eo = 0; eo < 4; ++eo) {
      const int e = e4 * 4 + eo;
      float4 wk = *(const float4*)(W_node + e * 384 + 4 * c);
      float4 wv = *(const float4*)(W_node + e * 384 + 128 + 4 * c);
      float4 wl = *(const float4*)(Wc + e * 128 + 4 * c);
#pragma unroll
      for (int k = 0; k < 7; ++k) {
        const float ev = (eo == 0) ? em[k].x : (eo == 1) ? em[k].y : (eo == 2) ? em[k].z : em[k].w;
        gk_r[k].x = fmaf(ev, wk.x, gk_r[k].x); gk_r[k].y = fmaf(ev, wk.y, gk_r[k].y);
        gk_r[k].z = fmaf(ev, wk.z, gk_r[k].z); gk_r[k].w = fmaf(ev, wk.w, gk_r[k].w);
        gv_r[k].x = fmaf(ev, wv.x, gv_r[k].x); gv_r[k].y = fmaf(ev, wv.y, gv_r[k].y);
        gv_r[k].z = fmaf(ev, wv.z, gv_r[k].z); gv_r[k].w = fmaf(ev, wv.w, gv_r[k].w);
        lk_r[k].x = fmaf(ev, wl.x, lk_r[k].x); lk_r[k].y = fmaf(ev, wl.y, lk_r[k].y);
        lk_r[k].z = fmaf(ev, wl.z, lk_r[k].z); lk_r[k].w = fmaf(ev, wl.w, lk_r[k].w);
      }
    }
  }

  // ---- E = emb @ W_step_bot (x0.25), then overwrite semb with it ----
  float4 accE[7];
#pragma unroll
  for (int k = 0; k < 7; ++k) accE[k] = make_float4(0, 0, 0, 0);
#pragma unroll 2
  for (int e4 = 0; e4 < 32; ++e4) {
    float4 em[7];
#pragma unroll
    for (int k = 0; k < 7; ++k) {
      int n = g + 16 * k; n = (n < 100) ? n : 99;
      em[k] = *(const float4*)(&semb[n][e4 * 4]);
    }
#pragma unroll
    for (int eo = 0; eo < 4; ++eo) {
      const int e = e4 * 4 + eo;
      float4 wb = *(const float4*)(W_step + (size_t)(128 + e) * 128 + 4 * c);
#pragma unroll
      for (int k = 0; k < 7; ++k) {
        const float ev = (eo == 0) ? em[k].x : (eo == 1) ? em[k].y : (eo == 2) ? em[k].z : em[k].w;
        accE[k].x = fmaf(ev, wb.x, accE[k].x); accE[k].y = fmaf(ev, wb.y, accE[k].y);
        accE[k].z = fmaf(ev, wb.z, accE[k].z); accE[k].w = fmaf(ev, wb.w, accE[k].w);
      }
    }
  }
  __syncthreads();  // all semb reads complete
#pragma unroll
  for (int k = 0; k < 7; ++k) {
    int n = g + 16 * k;
    if (n < 100) {
      float4 v;
      v.x = 0.25f * accE[k].x; v.y = 0.25f * accE[k].y;
      v.z = 0.25f * accE[k].z; v.w = 0.25f * accE[k].w;
      *(float4*)(&semb[n][4 * c]) = v;
    }
  }
  __syncthreads();
  const float* sE = &semb[0][0];  // semb now holds 0.25*E

  // ---- decode loop ----
  float4 F4 = make_float4(0, 0, 0, 0);
  unsigned mreg[4] = {0u, 0u, 0u, 0u};

#pragma unroll 1
  for (int t = 0; t < 100; ++t) {
    // (a) query quad (pre-scaled by 0.25)
    float4 sq4;
    if (t == 0) {
      sq4.x = ctx4.x + qp4.x; sq4.y = ctx4.y + qp4.y;
      sq4.z = ctx4.z + qp4.z; sq4.w = ctx4.w + qp4.w;
    } else {
      int lastn = si[0];
      float4 e4v = *(const float4*)(sE + lastn * 128 + 4 * c);
      sq4.x = ctx4.x + F4.x + e4v.x; sq4.y = ctx4.y + F4.y + e4v.y;
      sq4.z = ctx4.z + F4.z + e4v.z; sq4.w = ctx4.w + F4.w + e4v.w;
    }

    // (b) compat[h][n] = (q . gk_n)/4, masked
#pragma unroll
    for (int k = 0; k < 7; ++k) {
      int n = g + 16 * k;
      if (n < 100) {  // uniform within the 4-lane reduce group
        float v = sq4.x * gk_r[k].x;
        v = fmaf(sq4.y, gk_r[k].y, v);
        v = fmaf(sq4.z, gk_r[k].z, v);
        v = fmaf(sq4.w, gk_r[k].w, v);
        v += __shfl_xor(v, 1);
        v += __shfl_xor(v, 2);
        if ((c & 3) == 0) {
          bool msk = (mreg[n >> 5] >> (n & 31)) & 1u;
          scomp[h][n] = msk ? NEG_INF : v;
        }
      }
    }
    __syncthreads();  // B1

    // (c) softmax over n: wave `wave` owns head row h=wave
    {
      float va = -INFINITY, vb = -INFINITY;
      if (lane < 50) { va = scomp[wave][lane]; vb = scomp[wave][lane + 50]; }
      float m = fmaxf(va, vb);
#pragma unroll
      for (int off = 1; off < 64; off <<= 1) m = fmaxf(m, __shfl_xor(m, off));
      float ea = expf(va - m), eb = expf(vb - m);  // -inf -> 0
      float s = ea + eb;
#pragma unroll
      for (int off = 1; off < 64; off <<= 1) s += __shfl_xor(s, off);
      if (lane < 50) { scomp[wave][lane] = ea / s; scomp[wave][lane + 50] = eb / s; }
    }
    __syncthreads();  // B2

    // (d) heads[d] = sum_n attn[h][n]*gv[n][d]
    float hx = 0.f, hy = 0.f, hz = 0.f, hw = 0.f;
#pragma unroll
    for (int k = 0; k < 7; ++k) {
      int n = g + 16 * k;
      if (n < 100) {
        float av = scomp[h][n];
        hx = fmaf(av, gv_r[k].x, hx); hy = fmaf(av, gv_r[k].y, hy);
        hz = fmaf(av, gv_r[k].z, hz); hw = fmaf(av, gv_r[k].w, hw);
      }
    }
    hx += __shfl_xor(hx, 32); hy += __shfl_xor(hy, 32);
    hz += __shfl_xor(hz, 32); hw += __shfl_xor(hw, 32);
    if (lane < 32) { red[wave][c][0] = hx; red[wave][c][1] = hy; red[wave][c][2] = hz; red[wave][c][3] = hw; }
    __syncthreads();  // B3
    float4 head4;
    {
      float sx = 0.f, sy = 0.f, sz = 0.f, sw = 0.f;
      for (int ww = 0; ww < 8; ++ww) {
        sx += red[ww][c][0]; sy += red[ww][c][1]; sz += red[ww][c][2]; sw += red[ww][c][3];
      }
      head4.x = sx; head4.y = sy; head4.z = sz; head4.w = sw;
    }

    // (e) raw logits[n] = heads . lk'_n  (1/sqrt(128) folded into lk')
#pragma unroll
    for (int k = 0; k < 7; ++k) {
      int n = g + 16 * k;
      if (n < 100) {  // uniform within the 32-lane reduce group
        float v = head4.x * lk_r[k].x;
        v = fmaf(head4.y, lk_r[k].y, v);
        v = fmaf(head4.z, lk_r[k].z, v);
        v = fmaf(head4.w, lk_r[k].w, v);
        v += __shfl_xor(v, 1);  v += __shfl_xor(v, 2);
        v += __shfl_xor(v, 4);  v += __shfl_xor(v, 8);
        v += __shfl_xor(v, 16);
        if (c == 0) slog[n] = v;
      }
    }
    __syncthreads();  // B4

    // (f) tanh clip + mask
    if (tid < 100) {
      float tl = 10.0f * tanhf(slog[tid]);
      bool msk = (mreg[tid >> 5] >> (tid & 31)) & 1u;
      slog[tid] = msk ? NEG_INF : tl;
    }
    __syncthreads();  // B5

    // (g) wave0: max, logsumexp, argmax(log_p) with first-index tie-break
    if (wave == 0) {
      float va = (lane < 50) ? slog[lane] : -INFINITY;
      float vb = (lane < 50) ? slog[lane + 50] : -INFINITY;
      float m = fmaxf(va, vb);
#pragma unroll
      for (int off = 1; off < 64; off <<= 1) m = fmaxf(m, __shfl_xor(m, off));
      float ea = expf(va - m), eb = expf(vb - m);
      float s = ea + eb;
#pragma unroll
      for (int off = 1; off < 64; off <<= 1) s += __shfl_xor(s, off);
      float lsum = logf(s);
      float pa = (va - m) - lsum;
      float pb = (vb - m) - lsum;
      float bv; int bi_;
      if (pb > pa) { bv = pb; bi_ = lane + 50; } else { bv = pa; bi_ = lane; }
#pragma unroll
      for (int off = 1; off < 64; off <<= 1) {
        float ov = __shfl_xor(bv, off);
        int oi = __shfl_xor(bi_, off);
        if (ov > bv || (ov == bv && oi < bi_)) { bv = ov; bi_ = oi; }
      }
      if (lane == 0) {
        si[0] = bi_;
        if (t == 0) si[1] = bi_;
        sf[0] = m; sf[1] = lsum;
        out_pi[b * 100 + t] = (float)bi_;
      }
    }
    __syncthreads();  // B6

    // F = 0.25 * emb[first] @ W_step_top, once, after step 0
    if (t == 0) {
      int f0 = si[1];
      const float* erow = embB + (size_t)f0 * 128;
      float ax = 0.f, ay = 0.f, az = 0.f, aw = 0.f;
      for (int i = 0; i < 8; ++i) {
        int dd = g * 8 + i;
        float ev = erow[dd];
        float4 wq = *(const float4*)(W_step + (size_t)dd * 128 + 4 * c);
        ax = fmaf(ev, wq.x, ax); ay = fmaf(ev, wq.y, ay);
        az = fmaf(ev, wq.z, az); aw = fmaf(ev, wq.w, aw);
      }
      ax += __shfl_xor(ax, 32); ay += __shfl_xor(ay, 32);
      az += __shfl_xor(az, 32); aw += __shfl_xor(aw, 32);
      if (lane < 32) { red[wave][c][0] = ax; red[wave][c][1] = ay; red[wave][c][2] = az; red[wave][c][3] = aw; }
      __syncthreads();
      float sx = 0.f, sy = 0.f, sz = 0.f, sw = 0.f;
      for (int ww = 0; ww < 8; ++ww) {
        sx += red[ww][c][0]; sy += red[ww][c][1]; sz += red[ww][c][2]; sw += red[ww][c][3];
      }
      F4.x = 0.25f * sx; F4.y = 0.25f * sy; F4.z = 0.25f * sz; F4.w = 0.25f * sw;
      __syncthreads();
    }

    // (h) mask update + log_p row write
    {
      int sel = si[0];
      float m = sf[0], lsum = sf[1];
#pragma unroll
      for (int ww2 = 0; ww2 < 4; ++ww2)
        if ((sel >> 5) == ww2) mreg[ww2] |= (1u << (sel & 31));
      if (tid < 100) {
        float lp = (slog[tid] - m) - lsum;
        out_logp[(size_t)b * 10000 + (size_t)t * 100 + tid] = lp;
      }
    }
  }
}

extern "C" void kernel_launch(void* const* d_in, const int* in_sizes, int n_in,
                              void* d_out, int out_size, void* d_ws, size_t ws_size,
                              hipStream_t stream) {
  const float* emb     = (const float*)d_in[0];
  const float* W_node  = (const float*)d_in[1];
  const float* W_fixed = (const float*)d_in[2];
  const float* W_step  = (const float*)d_in[3];
  const float* W_out   = (const float*)d_in[4];
  const float* W_ph    = (const float*)d_in[5];
  float* ws  = (float*)d_ws;
  float* out = (float*)d_out;

  hipLaunchKernelGGL(pre_kernel, dim3(65), dim3(128), 0, stream,
                     W_node, W_out, W_step, W_ph, ws);
  hipLaunchKernelGGL(decode_kernel, dim3(2048), dim3(512), 0, stream,
                     emb, W_node, W_fixed, W_step, ws, out, out + 20480000);
}

// Round 2
// 4039.167 us; speedup vs baseline: 1.0018x; 1.0018x over previous
//
#include <hip/hip_runtime.h>
#include <math.h>

#define NEG_INF (-1e9f)

// ---------------------------------------------------------------------------
// pre_kernel: builds into ws
//   ws[0 .. 16383]   : Wc[e][d] = (1/sqrt(128)) * sum_j W_node[e,256+j]*W_out[d,j]
//   ws[16384..16511] : qp[d]    = sum_i W_placeholder[i]*W_step[i,d]
// ---------------------------------------------------------------------------
__global__ __launch_bounds__(128) void pre_kernel(
    const float* __restrict__ W_node, const float* __restrict__ W_out,
    const float* __restrict__ W_step, const float* __restrict__ W_ph,
    float* __restrict__ ws) {
  const int bi = blockIdx.x;
  const int tid = threadIdx.x;
  if (bi < 64) {
    __shared__ float woT[64][133];  // transposed W_out chunk, padded stride 133
    float acc0 = 0.f, acc1 = 0.f;
    const int e0 = bi * 2, e1 = e0 + 1;
    for (int ch = 0; ch < 2; ++ch) {
      const int j0 = ch * 64;
      for (int it = 0; it < 64; ++it) {
        int idx = tid + it * 128;           // 0..8191
        int jj = idx & 63, ds = idx >> 6;   // coalesced global read
        woT[jj][ds] = W_out[ds * 128 + j0 + jj];
      }
      __syncthreads();
      for (int jj = 0; jj < 64; ++jj) {
        int j = j0 + jj;
        float a0 = W_node[e0 * 384 + 256 + j];
        float a1 = W_node[e1 * 384 + 256 + j];
        float bb = woT[jj][tid];            // conflict-free (pad 133)
        acc0 = fmaf(a0, bb, acc0);
        acc1 = fmaf(a1, bb, acc1);
      }
      __syncthreads();
    }
    const float rs = 0.08838834764831845f;  // 1/sqrt(128)
    ws[e0 * 128 + tid] = acc0 * rs;
    ws[e1 * 128 + tid] = acc1 * rs;
  } else {
    float acc = 0.f;
    for (int i = 0; i < 256; ++i) acc = fmaf(W_ph[i], W_step[i * 128 + tid], acc);
    ws[16384 + tid] = acc;
  }
}

// ---------------------------------------------------------------------------
// decode_kernel: one block per batch row; 512 threads; loops t=0..99.
// Thread (c = tid&31, g = tid>>5): owns col-quad d=4c..4c+3 of rows n=g+16k.
// gk/gv/lk' register-resident (84 VGPRs). E = emb@W_step_bot in LDS
// (overwrites the emb staging area). 0.25 (1/sqrt(dk)) folded into query
// components; 1/sqrt(128) folded into Wc by pre_kernel.
// ---------------------------------------------------------------------------
__global__ __launch_bounds__(512) void decode_kernel(
    const float* __restrict__ emb,      // [2048][100][128]
    const float* __restrict__ W_node,   // [128][384]
    const float* __restrict__ W_fixed,  // [128][128]
    const float* __restrict__ W_step,   // [256][128]
    const float* __restrict__ ws,       // Wc + qp
    float* __restrict__ out_logp,       // [2048][100][100]
    float* __restrict__ out_pi) {       // [2048][100] (as float)
  const int b = blockIdx.x;
  const int tid = threadIdx.x;
  const int c = tid & 31;
  const int g = tid >> 5;   // 0..15
  const int h = c >> 2;     // head
  const int lane = tid & 63;
  const int wave = tid >> 6;  // 0..7

  __shared__ __align__(16) float semb[100][128];  // emb staging -> later E
  __shared__ __align__(16) float scomp[8][100];   // compat / attn
  __shared__ float slog[100];
  __shared__ __align__(16) float red[8][32][4];
  __shared__ float smean[128];
  __shared__ float sf[4];
  __shared__ int si[4];

  const float* embB = emb + (size_t)b * 12800;

  // ---- stage emb into LDS (coalesced float4) ----
  for (int it = 0; it < 7; ++it) {
    int qi = tid + it * 512;
    if (qi < 3200) ((float4*)&semb[0][0])[qi] = ((const float4*)embB)[qi];
  }
  __syncthreads();

  // ---- graph mean ----
  {
    int d = tid & 127, q = tid >> 7;
    float p = 0.f;
    for (int n = q * 25; n < q * 25 + 25; ++n) p += semb[n][d];
    ((float*)red)[q * 128 + d] = p;
  }
  __syncthreads();
  if (tid < 128) {
    float* rf = (float*)red;
    smean[tid] = (rf[tid] + rf[128 + tid] + rf[256 + tid] + rf[384 + tid]) / 100.0f;
  }
  __syncthreads();

  // ---- fixed_context quad (x0.25 folded) ----
  float4 ctx4;
  {
    float ax = 0.f, ay = 0.f, az = 0.f, aw = 0.f;
    for (int i = 0; i < 8; ++i) {
      int dd = g * 8 + i;
      float mv = smean[dd];
      float4 wq = *(const float4*)(W_fixed + dd * 128 + 4 * c);
      ax = fmaf(mv, wq.x, ax); ay = fmaf(mv, wq.y, ay);
      az = fmaf(mv, wq.z, az); aw = fmaf(mv, wq.w, aw);
    }
    ax += __shfl_xor(ax, 32); ay += __shfl_xor(ay, 32);
    az += __shfl_xor(az, 32); aw += __shfl_xor(aw, 32);
    if (lane < 32) { red[wave][c][0] = ax; red[wave][c][1] = ay; red[wave][c][2] = az; red[wave][c][3] = aw; }
    __syncthreads();
    float sx = 0.f, sy = 0.f, sz = 0.f, sw = 0.f;
    for (int ww = 0; ww < 8; ++ww) {
      sx += red[ww][c][0]; sy += red[ww][c][1]; sz += red[ww][c][2]; sw += red[ww][c][3];
    }
    ctx4.x = 0.25f * sx; ctx4.y = 0.25f * sy; ctx4.z = 0.25f * sz; ctx4.w = 0.25f * sw;
    __syncthreads();
  }

  // ---- qp quad (x0.25 folded) ----
  float4 qp4 = *(const float4*)(ws + 16384 + 4 * c);
  qp4.x *= 0.25f; qp4.y *= 0.25f; qp4.z *= 0.25f; qp4.w *= 0.25f;

  // ---- gk / gv / lk' into registers ----
  float4 gk_r[7], gv_r[7], lk_r[7];
#pragma unroll
  for (int k = 0; k < 7; ++k) {
    gk_r[k] = make_float4(0, 0, 0, 0);
    gv_r[k] = make_float4(0, 0, 0, 0);
    lk_r[k] = make_float4(0, 0, 0, 0);
  }
  const float* Wc = ws;
#pragma unroll 2
  for (int e4 = 0; e4 < 32; ++e4) {
    float4 em[7];
#pragma unroll
    for (int k = 0; k < 7; ++k) {
      int n = g + 16 * k; n = (n < 100) ? n : 99;
      em[k] = *(const float4*)(&semb[n][e4 * 4]);
    }
#pragma unroll
    for (int eo = 0; eo < 4; ++eo) {
      const int e = e4 * 4 + eo;
      float4 wk = *(const float4*)(W_node + e * 384 + 4 * c);
      float4 wv = *(const float4*)(W_node + e * 384 + 128 + 4 * c);
      float4 wl = *(const float4*)(Wc + e * 128 + 4 * c);
#pragma unroll
      for (int k = 0; k < 7; ++k) {
        const float ev = (eo == 0) ? em[k].x : (eo == 1) ? em[k].y : (eo == 2) ? em[k].z : em[k].w;
        gk_r[k].x = fmaf(ev, wk.x, gk_r[k].x); gk_r[k].y = fmaf(ev, wk.y, gk_r[k].y);
        gk_r[k].z = fmaf(ev, wk.z, gk_r[k].z); gk_r[k].w = fmaf(ev, wk.w, gk_r[k].w);
        gv_r[k].x = fmaf(ev, wv.x, gv_r[k].x); gv_r[k].y = fmaf(ev, wv.y, gv_r[k].y);
        gv_r[k].z = fmaf(ev, wv.z, gv_r[k].z); gv_r[k].w = fmaf(ev, wv.w, gv_r[k].w);
        lk_r[k].x = fmaf(ev, wl.x, lk_r[k].x); lk_r[k].y = fmaf(ev, wl.y, lk_r[k].y);
        lk_r[k].z = fmaf(ev, wl.z, lk_r[k].z); lk_r[k].w = fmaf(ev, wl.w, lk_r[k].w);
      }
    }
  }

  // ---- E = emb @ W_step_bot (x0.25), then overwrite semb with it ----
  float4 accE[7];
#pragma unroll
  for (int k = 0; k < 7; ++k) accE[k] = make_float4(0, 0, 0, 0);
#pragma unroll 2
  for (int e4 = 0; e4 < 32; ++e4) {
    float4 em[7];
#pragma unroll
    for (int k = 0; k < 7; ++k) {
      int n = g + 16 * k; n = (n < 100) ? n : 99;
      em[k] = *(const float4*)(&semb[n][e4 * 4]);
    }
#pragma unroll
    for (int eo = 0; eo < 4; ++eo) {
      const int e = e4 * 4 + eo;
      float4 wb = *(const float4*)(W_step + (size_t)(128 + e) * 128 + 4 * c);
#pragma unroll
      for (int k = 0; k < 7; ++k) {
        const float ev = (eo == 0) ? em[k].x : (eo == 1) ? em[k].y : (eo == 2) ? em[k].z : em[k].w;
        accE[k].x = fmaf(ev, wb.x, accE[k].x); accE[k].y = fmaf(ev, wb.y, accE[k].y);
        accE[k].z = fmaf(ev, wb.z, accE[k].z); accE[k].w = fmaf(ev, wb.w, accE[k].w);
      }
    }
  }
  __syncthreads();  // all semb reads complete
#pragma unroll
  for (int k = 0; k < 7; ++k) {
    int n = g + 16 * k;
    if (n < 100) {
      float4 v;
      v.x = 0.25f * accE[k].x; v.y = 0.25f * accE[k].y;
      v.z = 0.25f * accE[k].z; v.w = 0.25f * accE[k].w;
      *(float4*)(&semb[n][4 * c]) = v;
    }
  }
  __syncthreads();
  const float* sE = &semb[0][0];  // semb now holds 0.25*E

  // ---- decode loop ----
  float4 F4 = make_float4(0, 0, 0, 0);
  unsigned mreg[4] = {0u, 0u, 0u, 0u};

#pragma unroll 1
  for (int t = 0; t < 100; ++t) {
    // (a) query quad (pre-scaled by 0.25)
    float4 sq4;
    if (t == 0) {
      sq4.x = ctx4.x + qp4.x; sq4.y = ctx4.y + qp4.y;
      sq4.z = ctx4.z + qp4.z; sq4.w = ctx4.w + qp4.w;
    } else {
      int lastn = si[0];
      float4 e4v = *(const float4*)(sE + lastn * 128 + 4 * c);
      sq4.x = ctx4.x + F4.x + e4v.x; sq4.y = ctx4.y + F4.y + e4v.y;
      sq4.z = ctx4.z + F4.z + e4v.z; sq4.w = ctx4.w + F4.w + e4v.w;
    }

    // (b) compat[h][n] = (q . gk_n)/4, masked
#pragma unroll
    for (int k = 0; k < 7; ++k) {
      int n = g + 16 * k;
      if (n < 100) {  // uniform within the 4-lane reduce group
        float v = sq4.x * gk_r[k].x;
        v = fmaf(sq4.y, gk_r[k].y, v);
        v = fmaf(sq4.z, gk_r[k].z, v);
        v = fmaf(sq4.w, gk_r[k].w, v);
        v += __shfl_xor(v, 1);
        v += __shfl_xor(v, 2);
        if ((c & 3) == 0) {
          bool msk = (mreg[n >> 5] >> (n & 31)) & 1u;
          scomp[h][n] = msk ? NEG_INF : v;
        }
      }
    }
    __syncthreads();  // B1

    // (c) softmax over n: wave `wave` owns head row h=wave
    {
      float va = -INFINITY, vb = -INFINITY;
      if (lane < 50) { va = scomp[wave][lane]; vb = scomp[wave][lane + 50]; }
      float m = fmaxf(va, vb);
#pragma unroll
      for (int off = 1; off < 64; off <<= 1) m = fmaxf(m, __shfl_xor(m, off));
      float ea = expf(va - m), eb = expf(vb - m);  // -inf -> 0
      float s = ea + eb;
#pragma unroll
      for (int off = 1; off < 64; off <<= 1) s += __shfl_xor(s, off);
      if (lane < 50) { scomp[wave][lane] = ea / s; scomp[wave][lane + 50] = eb / s; }
    }
    __syncthreads();  // B2

    // (d) heads[d] = sum_n attn[h][n]*gv[n][d]
    float hx = 0.f, hy = 0.f, hz = 0.f, hw = 0.f;
#pragma unroll
    for (int k = 0; k < 7; ++k) {
      int n = g + 16 * k;
      if (n < 100) {
        float av = scomp[h][n];
        hx = fmaf(av, gv_r[k].x, hx); hy = fmaf(av, gv_r[k].y, hy);
        hz = fmaf(av, gv_r[k].z, hz); hw = fmaf(av, gv_r[k].w, hw);
      }
    }
    hx += __shfl_xor(hx, 32); hy += __shfl_xor(hy, 32);
    hz += __shfl_xor(hz, 32); hw += __shfl_xor(hw, 32);
    if (lane < 32) { red[wave][c][0] = hx; red[wave][c][1] = hy; red[wave][c][2] = hz; red[wave][c][3] = hw; }
    __syncthreads();  // B3
    float4 head4;
    {
      float sx = 0.f, sy = 0.f, sz = 0.f, sw = 0.f;
      for (int ww = 0; ww < 8; ++ww) {
        sx += red[ww][c][0]; sy += red[ww][c][1]; sz += red[ww][c][2]; sw += red[ww][c][3];
      }
      head4.x = sx; head4.y = sy; head4.z = sz; head4.w = sw;
    }

    // (e) raw logits[n] = heads . lk'_n  (1/sqrt(128) folded into lk')
#pragma unroll
    for (int k = 0; k < 7; ++k) {
      int n = g + 16 * k;
      if (n < 100) {  // uniform within the 32-lane reduce group
        float v = head4.x * lk_r[k].x;
        v = fmaf(head4.y, lk_r[k].y, v);
        v = fmaf(head4.z, lk_r[k].z, v);
        v = fmaf(head4.w, lk_r[k].w, v);
        v += __shfl_xor(v, 1);  v += __shfl_xor(v, 2);
        v += __shfl_xor(v, 4);  v += __shfl_xor(v, 8);
        v += __shfl_xor(v, 16);
        if (c == 0) slog[n] = v;
      }
    }
    __syncthreads();  // B4

    // (f) tanh clip + mask
    if (tid < 100) {
      float tl = 10.0f * tanhf(slog[tid]);
      bool msk = (mreg[tid >> 5] >> (tid & 31)) & 1u;
      slog[tid] = msk ? NEG_INF : tl;
    }
    __syncthreads();  // B5

    // (g) wave0: max, logsumexp, argmax(log_p) with first-index tie-break
    if (wave == 0) {
      float va = (lane < 50) ? slog[lane] : -INFINITY;
      float vb = (lane < 50) ? slog[lane + 50] : -INFINITY;
      float m = fmaxf(va, vb);
#pragma unroll
      for (int off = 1; off < 64; off <<= 1) m = fmaxf(m, __shfl_xor(m, off));
      float ea = expf(va - m), eb = expf(vb - m);
      float s = ea + eb;
#pragma unroll
      for (int off = 1; off < 64; off <<= 1) s += __shfl_xor(s, off);
      float lsum = logf(s);
      float pa = (va - m) - lsum;
      float pb = (vb - m) - lsum;
      float bv; int bi_;
      if (pb > pa) { bv = pb; bi_ = lane + 50; } else { bv = pa; bi_ = lane; }
#pragma unroll
      for (int off = 1; off < 64; off <<= 1) {
        float ov = __shfl_xor(bv, off);
        int oi = __shfl_xor(bi_, off);
        if (ov > bv || (ov == bv && oi < bi_)) { bv = ov; bi_ = oi; }
      }
      if (lane == 0) {
        si[0] = bi_;
        if (t == 0) si[1] = bi_;
        sf[0] = m; sf[1] = lsum;
        out_pi[b * 100 + t] = (float)bi_;
      }
    }
    __syncthreads();  // B6

    // F = 0.25 * emb[first] @ W_step_top, once, after step 0
    if (t == 0) {
      int f0 = si[1];
      const float* erow = embB + (size_t)f0 * 128;
      float ax = 0.f, ay = 0.f, az = 0.f, aw = 0.f;
      for (int i = 0; i < 8; ++i) {
        int dd = g * 8 + i;
        float ev = erow[dd];
        float4 wq = *(const float4*)(W_step + (size_t)dd * 128 + 4 * c);
        ax = fmaf(ev, wq.x, ax); ay = fmaf(ev, wq.y, ay);
        az = fmaf(ev, wq.z, az); aw = fmaf(ev, wq.w, aw);
      }
      ax += __shfl_xor(ax, 32); ay += __shfl_xor(ay, 32);
      az += __shfl_xor(az, 32); aw += __shfl_xor(aw, 32);
      if (lane < 32) { red[wave][c][0] = ax; red[wave][c][1] = ay; red[wave][c][2] = az; red[wave][c][3] = aw; }
      __syncthreads();
      float sx = 0.f, sy = 0.f, sz = 0.f, sw = 0.f;
      for (int ww = 0; ww < 8; ++ww) {
        sx += red[ww][c][0]; sy += red[ww][c][1]; sz += red[ww][c][2]; sw += red[ww][c][3];
      }
      F4.x = 0.25f * sx; F4.y = 0.25f * sy; F4.z = 0.25f * sz; F4.w = 0.25f * sw;
      __syncthreads();
    }

    // (h) mask update + log_p row write
    {
      int sel = si[0];
      float m = sf[0], lsum = sf[1];
#pragma unroll
      for (int ww2 = 0; ww2 < 4; ++ww2)
        if ((sel >> 5) == ww2) mreg[ww2] |= (1u << (sel & 31));
      if (tid < 100) {
        float lp = (slog[tid] - m) - lsum;
        out_logp[(size_t)b * 10000 + (size_t)t * 100 + tid] = lp;
      }
    }
  }
}

extern "C" void kernel_launch(void* const* d_in, const int* in_sizes, int n_in,
                              void* d_out, int out_size, void* d_ws, size_t ws_size,
                              hipStream_t stream) {
  const float* emb     = (const float*)d_in[0];
  const float* W_node  = (const float*)d_in[1];
  const float* W_fixed = (const float*)d_in[2];
  const float* W_step  = (const float*)d_in[3];
  const float* W_out   = (const float*)d_in[4];
  const float* W_ph    = (const float*)d_in[5];
  float* ws  = (float*)d_ws;
  float* out = (float*)d_out;

  hipLaunchKernelGGL(pre_kernel, dim3(65), dim3(128), 0, stream,
                     W_node, W_out, W_step, W_ph, ws);
  hipLaunchKernelGGL(decode_kernel, dim3(2048), dim3(512), 0, stream,
                     emb, W_node, W_fixed, W_step, ws, out, out + 20480000);
}

// Round 3
// 3438.472 us; speedup vs baseline: 1.1768x; 1.1747x over previous
//
#include <hip/hip_runtime.h>
#include <math.h>

#define NEG_INF (-1e9f)
#define WSYNC() asm volatile("s_waitcnt lgkmcnt(0)" ::: "memory")

// ---------------------------------------------------------------------------
// pre_kernel: builds into ws
//   ws[0 .. 16383]   : Wc[e][d] = (1/sqrt(128)) * sum_j W_node[e,256+j]*W_out[d,j]
//   ws[16384..16511] : qp[d]    = sum_i W_placeholder[i]*W_step[i,d]
// ---------------------------------------------------------------------------
__global__ __launch_bounds__(128) void pre_kernel(
    const float* __restrict__ W_node, const float* __restrict__ W_out,
    const float* __restrict__ W_step, const float* __restrict__ W_ph,
    float* __restrict__ ws) {
  const int bi = blockIdx.x;
  const int tid = threadIdx.x;
  if (bi < 64) {
    __shared__ float woT[64][133];
    float acc0 = 0.f, acc1 = 0.f;
    const int e0 = bi * 2, e1 = e0 + 1;
    for (int ch = 0; ch < 2; ++ch) {
      const int j0 = ch * 64;
      for (int it = 0; it < 64; ++it) {
        int idx = tid + it * 128;
        int jj = idx & 63, ds = idx >> 6;
        woT[jj][ds] = W_out[ds * 128 + j0 + jj];
      }
      __syncthreads();
      for (int jj = 0; jj < 64; ++jj) {
        int j = j0 + jj;
        float a0 = W_node[e0 * 384 + 256 + j];
        float a1 = W_node[e1 * 384 + 256 + j];
        float bb = woT[jj][tid];
        acc0 = fmaf(a0, bb, acc0);
        acc1 = fmaf(a1, bb, acc1);
      }
      __syncthreads();
    }
    const float rs = 0.08838834764831845f;  // 1/sqrt(128)
    ws[e0 * 128 + tid] = acc0 * rs;
    ws[e1 * 128 + tid] = acc1 * rs;
  } else {
    float acc = 0.f;
    for (int i = 0; i < 256; ++i) acc = fmaf(W_ph[i], W_step[i * 128 + tid], acc);
    ws[16384 + tid] = acc;
  }
}

// ---------------------------------------------------------------------------
// decode_kernel: one block (512 thr = 8 waves) per batch row.
// wave h = head h; lane l owns rows {l, l+50} (l<50 active).
// Registers: gk[2][16], lk'[2][16] (rows x head-slice), gvT[25]
//   (lane (d'=l&15, q=l>>4) holds gv[q*25+i][h*16+d']), ctx[16] (0.25-scaled,
//   F folded in after t=0). LDS: sE (=0.25*E, overwrites emb staging, layout
//   [8][100][16] head-major), pool{sattn, sheads, spart}.
// One __syncthreads per decode step (cross-wave logits partial sum,
// parity double-buffered). All other handoffs wave-private + lgkmcnt.
// ---------------------------------------------------------------------------
__global__ __launch_bounds__(512, 2) void decode_kernel(
    const float* __restrict__ emb,      // [2048][100][128]
    const float* __restrict__ W_node,   // [128][384]
    const float* __restrict__ W_fixed,  // [128][128]
    const float* __restrict__ W_step,   // [256][128]
    const float* __restrict__ ws,       // Wc + qp
    float* __restrict__ out_logp,       // [2048][100][100]
    float* __restrict__ out_pi) {       // [2048][100] (as float)
  const int b = blockIdx.x;
  const int tid = threadIdx.x;
  const int h = tid >> 6;       // wave == head
  const int l = tid & 63;       // lane
  const int dp = l & 15;        // d' within head slice
  const int qg = l >> 4;        // row-quarter group 0..3
  const bool act = (l < 50);
  const int r0 = act ? l : 0;
  const int r1 = act ? l + 50 : 0;
  const int qq0 = (l < 25) ? 0 : 1;   // attn quarter of r0
  const int ii0 = l - qq0 * 25;       // index within quarter

  __shared__ __align__(16) float semb[100][128];  // 51200 B; later sE[8][100][16]
  __shared__ __align__(16) float pool[3200];      // 12800 B multi-use
  __shared__ float smean[128];
  __shared__ __align__(16) float sbase[8][16];

  const float* embB = emb + (size_t)b * 12800;

  // ---- stage emb into LDS ----
  for (int it = 0; it < 7; ++it) {
    int qi = tid + it * 512;
    if (qi < 3200) ((float4*)&semb[0][0])[qi] = ((const float4*)embB)[qi];
  }
  __syncthreads();

  // ---- graph mean (pool as scratch) ----
  {
    int d = tid & 127, q2 = tid >> 7;
    float p = 0.f;
    for (int n = q2 * 25; n < q2 * 25 + 25; ++n) p += semb[n][d];
    pool[q2 * 128 + d] = p;
  }
  __syncthreads();
  if (tid < 128)
    smean[tid] = (pool[tid] + pool[128 + tid] + pool[256 + tid] + pool[384 + tid]) * 0.01f;
  __syncthreads();

  // ---- ctx[16] = 0.25 * (mean @ W_fixed) head-slice, replicated per lane ----
  float ctx[16];
  {
    float a = 0.f;
    for (int i = 0; i < 32; ++i) {
      int e = qg * 32 + i;
      a = fmaf(smean[e], W_fixed[e * 128 + h * 16 + dp], a);
    }
    a += __shfl_xor(a, 16);
    a += __shfl_xor(a, 32);
    if (l < 16) sbase[h][l] = 0.25f * a;
    WSYNC();
#pragma unroll
    for (int jj = 0; jj < 4; ++jj) {
      float4 v = *(const float4*)&sbase[h][jj * 4];
      ctx[jj * 4 + 0] = v.x; ctx[jj * 4 + 1] = v.y;
      ctx[jj * 4 + 2] = v.z; ctx[jj * 4 + 3] = v.w;
    }
  }

  // ---- qp (0.25-scaled) ----
  float qpv[16];
#pragma unroll
  for (int jj = 0; jj < 4; ++jj) {
    float4 v = *(const float4*)&ws[16384 + h * 16 + jj * 4];
    qpv[jj * 4 + 0] = 0.25f * v.x; qpv[jj * 4 + 1] = 0.25f * v.y;
    qpv[jj * 4 + 2] = 0.25f * v.z; qpv[jj * 4 + 3] = 0.25f * v.w;
  }

  // ---- build tables: gk, gv(row), lk', E for rows r0,r1 over head slice ----
  float gk0[16], gk1[16], gv0[16], gv1[16], lk0[16], lk1[16], Ea0[16], Ea1[16];
#pragma unroll
  for (int j = 0; j < 16; ++j) {
    gk0[j] = gk1[j] = gv0[j] = gv1[j] = 0.f;
    lk0[j] = lk1[j] = Ea0[j] = Ea1[j] = 0.f;
  }
#pragma unroll 2
  for (int e4 = 0; e4 < 32; ++e4) {
    float4 a0 = *(const float4*)&semb[r0][e4 * 4];
    float4 a1 = *(const float4*)&semb[r1][e4 * 4];
    float em0[4] = {a0.x, a0.y, a0.z, a0.w};
    float em1[4] = {a1.x, a1.y, a1.z, a1.w};
#pragma unroll
    for (int eo = 0; eo < 4; ++eo) {
      const int e = e4 * 4 + eo;
      const float ev0 = em0[eo], ev1 = em1[eo];
      const float* wk = &W_node[e * 384 + h * 16];
      const float* wv = wk + 128;
      const float* wl = &ws[e * 128 + h * 16];
      const float* wE = &W_step[(size_t)(128 + e) * 128 + h * 16];
#pragma unroll
      for (int j = 0; j < 16; ++j) {
        float wkj = wk[j], wvj = wv[j], wlj = wl[j], wEj = wE[j];
        gk0[j] = fmaf(ev0, wkj, gk0[j]); gk1[j] = fmaf(ev1, wkj, gk1[j]);
        gv0[j] = fmaf(ev0, wvj, gv0[j]); gv1[j] = fmaf(ev1, wvj, gv1[j]);
        lk0[j] = fmaf(ev0, wlj, lk0[j]); lk1[j] = fmaf(ev1, wlj, lk1[j]);
        Ea0[j] = fmaf(ev0, wEj, Ea0[j]); Ea1[j] = fmaf(ev1, wEj, Ea1[j]);
      }
    }
  }
  __syncthreads();  // all semb reads complete block-wide

  // ---- sE[h][n][j] = 0.25*E[n][h*16+j] (overwrites semb; wave-private slice) ----
  float* sE = &semb[0][0];
  if (act) {
    float4* d0 = (float4*)(sE + (h * 100 + r0) * 16);
    float4* d1 = (float4*)(sE + (h * 100 + r1) * 16);
#pragma unroll
    for (int jj = 0; jj < 4; ++jj) {
      d0[jj] = make_float4(0.25f * Ea0[jj * 4], 0.25f * Ea0[jj * 4 + 1],
                           0.25f * Ea0[jj * 4 + 2], 0.25f * Ea0[jj * 4 + 3]);
      d1[jj] = make_float4(0.25f * Ea1[jj * 4], 0.25f * Ea1[jj * 4 + 1],
                           0.25f * Ea1[jj * 4 + 2], 0.25f * Ea1[jj * 4 + 3]);
    }
  }

  // ---- transpose gv into gvt[25]: lane (dp,qg) <- gv[qg*25+i][h*16+dp] ----
  float gvt[25];
  {
    float* gvtmp = pool;  // [8][25][16], wave-private slice h
#pragma unroll 1
    for (int pass = 0; pass < 4; ++pass) {
      WSYNC();
      if (act) {
        if (qq0 == pass) {
          float4* w = (float4*)(gvtmp + (h * 25 + ii0) * 16);
#pragma unroll
          for (int jj = 0; jj < 4; ++jj)
            w[jj] = make_float4(gv0[jj * 4], gv0[jj * 4 + 1], gv0[jj * 4 + 2], gv0[jj * 4 + 3]);
        }
        if (qq0 + 2 == pass) {
          float4* w = (float4*)(gvtmp + (h * 25 + ii0) * 16);
#pragma unroll
          for (int jj = 0; jj < 4; ++jj)
            w[jj] = make_float4(gv1[jj * 4], gv1[jj * 4 + 1], gv1[jj * 4 + 2], gv1[jj * 4 + 3]);
        }
      }
      WSYNC();
      if (qg == pass) {
#pragma unroll
        for (int i = 0; i < 25; ++i) gvt[i] = gvtmp[(h * 25 + i) * 16 + dp];
      }
    }
  }
  __syncthreads();  // pool repurposed: sattn/sheads/spart from here on

  // pool layout (floats): sattn = pool + h*112 + qq*28 (+i), per head 4x28
  //                       sheads = pool + 896 + h*16
  //                       spart  = pool + 1024 + par*1000 + n*10 + h
  float* sattnH = pool + h * 112;
  float* sheadsH = pool + 896 + h * 16;
  float* spartB = pool + 1024;

  // ---- decode loop ----
  bool m0f = false, m1f = false;
  int last = 0;
  int par = 0;
  const size_t lpbase = (size_t)b * 10000;

#pragma unroll 1
  for (int t = 0; t < 100; ++t) {
    // (a) query (0.25-scaled)
    float q[16];
    if (t == 0) {
#pragma unroll
      for (int j = 0; j < 16; ++j) q[j] = ctx[j] + qpv[j];
    } else {
      const float4* ep = (const float4*)(sE + (h * 100 + last) * 16);
#pragma unroll
      for (int jj = 0; jj < 4; ++jj) {
        float4 v = ep[jj];
        q[jj * 4 + 0] = ctx[jj * 4 + 0] + v.x;
        q[jj * 4 + 1] = ctx[jj * 4 + 1] + v.y;
        q[jj * 4 + 2] = ctx[jj * 4 + 2] + v.z;
        q[jj * 4 + 3] = ctx[jj * 4 + 3] + v.w;
      }
    }

    // (b) compat for my two rows (split accumulators for latency)
    float c0a = 0.f, c0b = 0.f, c1a = 0.f, c1b = 0.f;
#pragma unroll
    for (int j = 0; j < 8; ++j) {
      c0a = fmaf(q[j], gk0[j], c0a);
      c0b = fmaf(q[j + 8], gk0[j + 8], c0b);
      c1a = fmaf(q[j], gk1[j], c1a);
      c1b = fmaf(q[j + 8], gk1[j + 8], c1b);
    }
    float v0 = (act && !m0f) ? (c0a + c0b) : NEG_INF;
    float v1 = (act && !m1f) ? (c1a + c1b) : NEG_INF;

    // (c) in-wave softmax over 100 rows
    float mx = fmaxf(v0, v1);
#pragma unroll
    for (int off = 1; off < 64; off <<= 1) mx = fmaxf(mx, __shfl_xor(mx, off));
    float e0 = expf(v0 - mx), e1 = expf(v1 - mx);
    float s = e0 + e1;
#pragma unroll
    for (int off = 1; off < 64; off <<= 1) s += __shfl_xor(s, off);
    float a0 = e0 / s, a1 = e1 / s;

    // (d) attn -> wave-private LDS
    if (act) {
      sattnH[qq0 * 28 + ii0] = a0;
      sattnH[(qq0 + 2) * 28 + ii0] = a1;
    }
    WSYNC();

    // (e) heads: lane (dp,qg) accumulates over its 25 rows, 2-level reduce
    float av[25];
    {
      const float* ap = sattnH + qg * 28;
#pragma unroll
      for (int ii = 0; ii < 6; ++ii) {
        float4 v = ((const float4*)ap)[ii];
        av[4 * ii + 0] = v.x; av[4 * ii + 1] = v.y;
        av[4 * ii + 2] = v.z; av[4 * ii + 3] = v.w;
      }
      av[24] = ap[24];
    }
    float ha = 0.f, hb = 0.f;
#pragma unroll
    for (int i = 0; i < 12; ++i) {
      ha = fmaf(av[2 * i], gvt[2 * i], ha);
      hb = fmaf(av[2 * i + 1], gvt[2 * i + 1], hb);
    }
    ha = fmaf(av[24], gvt[24], ha);
    float hacc = ha + hb;
    hacc += __shfl_xor(hacc, 16);
    hacc += __shfl_xor(hacc, 32);
    if (l < 16) sheadsH[l] = hacc;
    WSYNC();
    float hd[16];
#pragma unroll
    for (int jj = 0; jj < 4; ++jj) {
      float4 v = *(const float4*)&sheadsH[jj * 4];
      hd[jj * 4 + 0] = v.x; hd[jj * 4 + 1] = v.y;
      hd[jj * 4 + 2] = v.z; hd[jj * 4 + 3] = v.w;
    }

    // (f) logits partial for my rows over this wave's 16 d
    float p0a = 0.f, p0b = 0.f, p1a = 0.f, p1b = 0.f;
#pragma unroll
    for (int j = 0; j < 8; ++j) {
      p0a = fmaf(hd[j], lk0[j], p0a);
      p0b = fmaf(hd[j + 8], lk0[j + 8], p0b);
      p1a = fmaf(hd[j], lk1[j], p1a);
      p1b = fmaf(hd[j + 8], lk1[j + 8], p1b);
    }
    if (act) {
      spartB[par * 1000 + r0 * 10 + h] = p0a + p0b;
      spartB[par * 1000 + r1 * 10 + h] = p1a + p1b;
    }
    __syncthreads();  // THE barrier

    // (g) final logits: sum 8 wave-partials, tanh-clip, mask
    const float* pr0 = spartB + par * 1000 + r0 * 10;
    const float* pr1 = spartB + par * 1000 + r1 * 10;
    float2 x0 = *(const float2*)pr0, x1 = *(const float2*)(pr0 + 2);
    float2 x2 = *(const float2*)(pr0 + 4), x3 = *(const float2*)(pr0 + 6);
    float2 y0 = *(const float2*)pr1, y1 = *(const float2*)(pr1 + 2);
    float2 y2 = *(const float2*)(pr1 + 4), y3 = *(const float2*)(pr1 + 6);
    float s0 = ((x0.x + x0.y) + (x1.x + x1.y)) + ((x2.x + x2.y) + (x3.x + x3.y));
    float s1 = ((y0.x + y0.y) + (y1.x + y1.y)) + ((y2.x + y2.y) + (y3.x + y3.y));
    float l0 = (act && !m0f) ? 10.0f * tanhf(s0) : NEG_INF;
    float l1 = (act && !m1f) ? 10.0f * tanhf(s1) : NEG_INF;

    // (h) in-wave LSE + argmax (argmax on logits == argmax on log_p)
    float mx2 = fmaxf(l0, l1);
#pragma unroll
    for (int off = 1; off < 64; off <<= 1) mx2 = fmaxf(mx2, __shfl_xor(mx2, off));
    float z = expf(l0 - mx2) + expf(l1 - mx2);
#pragma unroll
    for (int off = 1; off < 64; off <<= 1) z += __shfl_xor(z, off);
    float lsum = logf(z);
    float bv; int bi;
    if (l1 > l0) { bv = l1; bi = r1; } else { bv = l0; bi = act ? r0 : 1000; }
#pragma unroll
    for (int off = 1; off < 64; off <<= 1) {
      float ov = __shfl_xor(bv, off);
      int oi = __shfl_xor(bi, off);
      if (ov > bv || (ov == bv && oi < bi)) { bv = ov; bi = oi; }
    }
    const int sel = bi;  // identical in every lane of every wave

    // (i) outputs (wave 0 only)
    if (h == 0) {
      if (l == 0) out_pi[b * 100 + t] = (float)sel;
      if (act) {
        out_logp[lpbase + (size_t)t * 100 + r0] = (l0 - mx2) - lsum;
        out_logp[lpbase + (size_t)t * 100 + r1] = (l1 - mx2) - lsum;
      }
    }

    // (j) t==0: fold F = 0.25*emb[first]@W_step_top into ctx
    if (t == 0) {
      const float* erow = embB + (size_t)sel * 128;
      float fa = 0.f;
      for (int i = 0; i < 32; ++i) {
        int e = qg * 32 + i;
        fa = fmaf(erow[e], W_step[(size_t)e * 128 + h * 16 + dp], fa);
      }
      fa += __shfl_xor(fa, 16);
      fa += __shfl_xor(fa, 32);
      if (l < 16) sbase[h][l] = 0.25f * fa;
      WSYNC();
#pragma unroll
      for (int jj = 0; jj < 4; ++jj) {
        float4 v = *(const float4*)&sbase[h][jj * 4];
        ctx[jj * 4 + 0] += v.x; ctx[jj * 4 + 1] += v.y;
        ctx[jj * 4 + 2] += v.z; ctx[jj * 4 + 3] += v.w;
      }
    }

    // (k) mask update + carry
    m0f = m0f || (act && sel == r0);
    m1f = m1f || (act && sel == r1);
    last = sel;
    par ^= 1;
  }
}

extern "C" void kernel_launch(void* const* d_in, const int* in_sizes, int n_in,
                              void* d_out, int out_size, void* d_ws, size_t ws_size,
                              hipStream_t stream) {
  const float* emb     = (const float*)d_in[0];
  const float* W_node  = (const float*)d_in[1];
  const float* W_fixed = (const float*)d_in[2];
  const float* W_step  = (const float*)d_in[3];
  const float* W_out   = (const float*)d_in[4];
  const float* W_ph    = (const float*)d_in[5];
  float* ws  = (float*)d_ws;
  float* out = (float*)d_out;

  hipLaunchKernelGGL(pre_kernel, dim3(65), dim3(128), 0, stream,
                     W_node, W_out, W_step, W_ph, ws);
  hipLaunchKernelGGL(decode_kernel, dim3(2048), dim3(512), 0, stream,
                     emb, W_node, W_fixed, W_step, ws, out, out + 20480000);
}

// Round 4
// 3127.746 us; speedup vs baseline: 1.2938x; 1.0993x over previous
//
#include <hip/hip_runtime.h>
#include <math.h>

#define NEG_INF (-1e9f)
#define WSYNC() asm volatile("s_waitcnt lgkmcnt(0)" ::: "memory")

// ---------------------------------------------------------------------------
// pre_kernel: builds into ws
//   ws[0 .. 16383]   : Wc[e][d] = (1/sqrt(128)) * sum_j W_node[e,256+j]*W_out[d,j]
//   ws[16384..16511] : qp[d]    = sum_i W_placeholder[i]*W_step[i,d]
// ---------------------------------------------------------------------------
__global__ __launch_bounds__(128) void pre_kernel(
    const float* __restrict__ W_node, const float* __restrict__ W_out,
    const float* __restrict__ W_step, const float* __restrict__ W_ph,
    float* __restrict__ ws) {
  const int bi = blockIdx.x;
  const int tid = threadIdx.x;
  if (bi < 64) {
    __shared__ float woT[64][133];
    float acc0 = 0.f, acc1 = 0.f;
    const int e0 = bi * 2, e1 = e0 + 1;
    for (int ch = 0; ch < 2; ++ch) {
      const int j0 = ch * 64;
      for (int it = 0; it < 64; ++it) {
        int idx = tid + it * 128;
        int jj = idx & 63, ds = idx >> 6;
        woT[jj][ds] = W_out[ds * 128 + j0 + jj];
      }
      __syncthreads();
      for (int jj = 0; jj < 64; ++jj) {
        int j = j0 + jj;
        float a0 = W_node[e0 * 384 + 256 + j];
        float a1 = W_node[e1 * 384 + 256 + j];
        float bb = woT[jj][tid];
        acc0 = fmaf(a0, bb, acc0);
        acc1 = fmaf(a1, bb, acc1);
      }
      __syncthreads();
    }
    const float rs = 0.08838834764831845f;  // 1/sqrt(128)
    ws[e0 * 128 + tid] = acc0 * rs;
    ws[e1 * 128 + tid] = acc1 * rs;
  } else {
    float acc = 0.f;
    for (int i = 0; i < 256; ++i) acc = fmaf(W_ph[i], W_step[i * 128 + tid], acc);
    ws[16384 + tid] = acc;
  }
}

// ---------------------------------------------------------------------------
// decode_kernel: one block (512 thr = 8 waves) per batch row.
// wave h = head h; lane l owns rows {l, l+50} (l<50 active).
// __launch_bounds__(512) (NOT ,2): round-3's 128-VGPR cap caused ~0.65 GB of
// scratch spill traffic per dispatch. Live set ~190 regs -> needs the 256 cap.
// semb is chunk-XOR-swizzled (chunk ^= row&7) during the init phase so the
// lane=row table-build reads don't hit the stride-128 same-bank pattern.
// spart partials are [par][h][100] (lane-consecutive) -> conflict-free.
// One __syncthreads per decode step.
// ---------------------------------------------------------------------------
__global__ __launch_bounds__(512) void decode_kernel(
    const float* __restrict__ emb,      // [2048][100][128]
    const float* __restrict__ W_node,   // [128][384]
    const float* __restrict__ W_fixed,  // [128][128]
    const float* __restrict__ W_step,   // [256][128]
    const float* __restrict__ ws,       // Wc + qp
    float* __restrict__ out_logp,       // [2048][100][100]
    float* __restrict__ out_pi) {       // [2048][100] (as float)
  const int b = blockIdx.x;
  const int tid = threadIdx.x;
  const int h = tid >> 6;       // wave == head
  const int l = tid & 63;       // lane
  const int dp = l & 15;        // d' within head slice
  const int qg = l >> 4;        // row-quarter group 0..3
  const bool act = (l < 50);
  const int r0 = act ? l : 0;
  const int r1 = act ? l + 50 : 0;
  const int qq0 = (l < 25) ? 0 : 1;   // attn quarter of r0
  const int ii0 = l - qq0 * 25;       // index within quarter

  __shared__ __align__(16) float semb[100][128];  // 51200 B; later sE[8][100][16]
  __shared__ __align__(16) float pool[3200];      // 12800 B multi-use
  __shared__ float smean[128];
  __shared__ __align__(16) float sbase[8][16];

  const float* embB = emb + (size_t)b * 12800;
  float* sembf = &semb[0][0];
  float4* semb4 = (float4*)sembf;

  // ---- stage emb into LDS, chunk-swizzled: phys_chunk = c ^ (n&7) ----
  for (int it = 0; it < 7; ++it) {
    int qi = tid + it * 512;
    if (qi < 3200) {
      int n = qi >> 5, c = qi & 31;
      semb4[n * 32 + (c ^ (n & 7))] = ((const float4*)embB)[qi];
    }
  }
  __syncthreads();

  // ---- graph mean (pool as scratch) ----
  {
    int d = tid & 127, q2 = tid >> 7;
    int ch = d >> 2, cl = d & 3;
    float p = 0.f;
    for (int n = q2 * 25; n < q2 * 25 + 25; ++n)
      p += sembf[n * 128 + ((ch ^ (n & 7)) << 2) + cl];
    pool[q2 * 128 + d] = p;
  }
  __syncthreads();
  if (tid < 128)
    smean[tid] = (pool[tid] + pool[128 + tid] + pool[256 + tid] + pool[384 + tid]) * 0.01f;
  __syncthreads();

  // ---- ctx[16] = 0.25 * (mean @ W_fixed) head-slice, replicated per lane ----
  float ctx[16];
  {
    float a = 0.f;
    for (int i = 0; i < 32; ++i) {
      int e = qg * 32 + i;
      a = fmaf(smean[e], W_fixed[e * 128 + h * 16 + dp], a);
    }
    a += __shfl_xor(a, 16);
    a += __shfl_xor(a, 32);
    if (l < 16) sbase[h][l] = 0.25f * a;
    WSYNC();
#pragma unroll
    for (int jj = 0; jj < 4; ++jj) {
      float4 v = *(const float4*)&sbase[h][jj * 4];
      ctx[jj * 4 + 0] = v.x; ctx[jj * 4 + 1] = v.y;
      ctx[jj * 4 + 2] = v.z; ctx[jj * 4 + 3] = v.w;
    }
  }

  // ---- build tables: gk, gv(row), lk', E for rows r0,r1 over head slice ----
  float gk0[16], gk1[16], gv0[16], gv1[16], lk0[16], lk1[16], Ea0[16], Ea1[16];
#pragma unroll
  for (int j = 0; j < 16; ++j) {
    gk0[j] = gk1[j] = gv0[j] = gv1[j] = 0.f;
    lk0[j] = lk1[j] = Ea0[j] = Ea1[j] = 0.f;
  }
#pragma unroll 2
  for (int e4 = 0; e4 < 32; ++e4) {
    float4 a0 = semb4[r0 * 32 + (e4 ^ (r0 & 7))];
    float4 a1 = semb4[r1 * 32 + (e4 ^ (r1 & 7))];
    float em0[4] = {a0.x, a0.y, a0.z, a0.w};
    float em1[4] = {a1.x, a1.y, a1.z, a1.w};
#pragma unroll
    for (int eo = 0; eo < 4; ++eo) {
      const int e = e4 * 4 + eo;
      const float ev0 = em0[eo], ev1 = em1[eo];
      const float* wk = &W_node[e * 384 + h * 16];
      const float* wv = wk + 128;
      const float* wl = &ws[e * 128 + h * 16];
      const float* wE = &W_step[(size_t)(128 + e) * 128 + h * 16];
#pragma unroll
      for (int j = 0; j < 16; ++j) {
        float wkj = wk[j], wvj = wv[j], wlj = wl[j], wEj = wE[j];
        gk0[j] = fmaf(ev0, wkj, gk0[j]); gk1[j] = fmaf(ev1, wkj, gk1[j]);
        gv0[j] = fmaf(ev0, wvj, gv0[j]); gv1[j] = fmaf(ev1, wvj, gv1[j]);
        lk0[j] = fmaf(ev0, wlj, lk0[j]); lk1[j] = fmaf(ev1, wlj, lk1[j]);
        Ea0[j] = fmaf(ev0, wEj, Ea0[j]); Ea1[j] = fmaf(ev1, wEj, Ea1[j]);
      }
    }
  }
  __syncthreads();  // all semb reads complete block-wide

  // ---- sE[h][n][j] = 0.25*E[n][h*16+j] (overwrites semb; plain layout) ----
  float* sE = sembf;
  if (act) {
    float4* d0 = (float4*)(sE + (h * 100 + r0) * 16);
    float4* d1 = (float4*)(sE + (h * 100 + r1) * 16);
#pragma unroll
    for (int jj = 0; jj < 4; ++jj) {
      d0[jj] = make_float4(0.25f * Ea0[jj * 4], 0.25f * Ea0[jj * 4 + 1],
                           0.25f * Ea0[jj * 4 + 2], 0.25f * Ea0[jj * 4 + 3]);
      d1[jj] = make_float4(0.25f * Ea1[jj * 4], 0.25f * Ea1[jj * 4 + 1],
                           0.25f * Ea1[jj * 4 + 2], 0.25f * Ea1[jj * 4 + 3]);
    }
  }

  // ---- transpose gv into gvt[25]: lane (dp,qg) <- gv[qg*25+i][h*16+dp] ----
  float gvt[25];
  {
    float* gvtmp = pool;  // [8][25][16], wave-private slice h
#pragma unroll 1
    for (int pass = 0; pass < 4; ++pass) {
      WSYNC();
      if (act) {
        if (qq0 == pass) {
          float4* w = (float4*)(gvtmp + (h * 25 + ii0) * 16);
#pragma unroll
          for (int jj = 0; jj < 4; ++jj)
            w[jj] = make_float4(gv0[jj * 4], gv0[jj * 4 + 1], gv0[jj * 4 + 2], gv0[jj * 4 + 3]);
        }
        if (qq0 + 2 == pass) {
          float4* w = (float4*)(gvtmp + (h * 25 + ii0) * 16);
#pragma unroll
          for (int jj = 0; jj < 4; ++jj)
            w[jj] = make_float4(gv1[jj * 4], gv1[jj * 4 + 1], gv1[jj * 4 + 2], gv1[jj * 4 + 3]);
        }
      }
      WSYNC();
      if (qg == pass) {
#pragma unroll
        for (int i = 0; i < 25; ++i) gvt[i] = gvtmp[(h * 25 + i) * 16 + dp];
      }
    }
  }
  __syncthreads();  // pool repurposed below

  // pool layout (floats): sattn  = pool + h*112 (4 quarters x 28)
  //                       sheads = pool + 896 + h*16
  //                       spart  = pool + 1024 + par*800 + h*100 + n
  //                       sqp    = pool + 2624 + h*16   (0.25*qp, wave copy)
  float* sattnH = pool + h * 112;
  float* sheadsH = pool + 896 + h * 16;
  float* spartB = pool + 1024;
  float* sqpH = pool + 2624 + h * 16;

  if (l < 16) sqpH[l] = 0.25f * ws[16384 + h * 16 + l];
  WSYNC();

  // ---- decode loop ----
  bool m0f = false, m1f = false;
  int last = 0;
  int par = 0;
  const size_t lpbase = (size_t)b * 10000;

#pragma unroll 1
  for (int t = 0; t < 100; ++t) {
    // (a,b) query + compat for my two rows (q folded into the fma loop)
    const float* epf = (t == 0) ? sqpH : (sE + (h * 100 + last) * 16);
    const float4* ep = (const float4*)epf;
    float c0a = 0.f, c0b = 0.f, c1a = 0.f, c1b = 0.f;
#pragma unroll
    for (int jj = 0; jj < 2; ++jj) {
      float4 v = ep[jj];
      float q0 = ctx[4 * jj + 0] + v.x, q1 = ctx[4 * jj + 1] + v.y;
      float q2_ = ctx[4 * jj + 2] + v.z, q3 = ctx[4 * jj + 3] + v.w;
      c0a = fmaf(q0, gk0[4 * jj + 0], c0a); c1a = fmaf(q0, gk1[4 * jj + 0], c1a);
      c0a = fmaf(q1, gk0[4 * jj + 1], c0a); c1a = fmaf(q1, gk1[4 * jj + 1], c1a);
      c0a = fmaf(q2_, gk0[4 * jj + 2], c0a); c1a = fmaf(q2_, gk1[4 * jj + 2], c1a);
      c0a = fmaf(q3, gk0[4 * jj + 3], c0a); c1a = fmaf(q3, gk1[4 * jj + 3], c1a);
    }
#pragma unroll
    for (int jj = 2; jj < 4; ++jj) {
      float4 v = ep[jj];
      float q0 = ctx[4 * jj + 0] + v.x, q1 = ctx[4 * jj + 1] + v.y;
      float q2_ = ctx[4 * jj + 2] + v.z, q3 = ctx[4 * jj + 3] + v.w;
      c0b = fmaf(q0, gk0[4 * jj + 0], c0b); c1b = fmaf(q0, gk1[4 * jj + 0], c1b);
      c0b = fmaf(q1, gk0[4 * jj + 1], c0b); c1b = fmaf(q1, gk1[4 * jj + 1], c1b);
      c0b = fmaf(q2_, gk0[4 * jj + 2], c0b); c1b = fmaf(q2_, gk1[4 * jj + 2], c1b);
      c0b = fmaf(q3, gk0[4 * jj + 3], c0b); c1b = fmaf(q3, gk1[4 * jj + 3], c1b);
    }
    float v0 = (act && !m0f) ? (c0a + c0b) : NEG_INF;
    float v1 = (act && !m1f) ? (c1a + c1b) : NEG_INF;

    // (c) in-wave softmax over 100 rows
    float mx = fmaxf(v0, v1);
#pragma unroll
    for (int off = 1; off < 64; off <<= 1) mx = fmaxf(mx, __shfl_xor(mx, off));
    float e0 = expf(v0 - mx), e1 = expf(v1 - mx);
    float s = e0 + e1;
#pragma unroll
    for (int off = 1; off < 64; off <<= 1) s += __shfl_xor(s, off);
    float a0 = e0 / s, a1 = e1 / s;

    // (d) attn -> wave-private LDS
    if (act) {
      sattnH[qq0 * 28 + ii0] = a0;
      sattnH[(qq0 + 2) * 28 + ii0] = a1;
    }
    WSYNC();

    // (e) heads: lane (dp,qg) accumulates its 25 rows (loads folded into fma)
    {
      const float* ap = sattnH + qg * 28;
      float ha = 0.f, hb = 0.f;
#pragma unroll
      for (int ii = 0; ii < 6; ++ii) {
        float4 v = ((const float4*)ap)[ii];
        ha = fmaf(v.x, gvt[4 * ii + 0], ha);
        hb = fmaf(v.y, gvt[4 * ii + 1], hb);
        ha = fmaf(v.z, gvt[4 * ii + 2], ha);
        hb = fmaf(v.w, gvt[4 * ii + 3], hb);
      }
      ha = fmaf(ap[24], gvt[24], ha);
      float hacc = ha + hb;
      hacc += __shfl_xor(hacc, 16);
      hacc += __shfl_xor(hacc, 32);
      if (l < 16) sheadsH[l] = hacc;
    }
    WSYNC();

    // (f) logits partial for my rows over this wave's 16 d (hd folded)
    float p0a = 0.f, p0b = 0.f, p1a = 0.f, p1b = 0.f;
#pragma unroll
    for (int jj = 0; jj < 2; ++jj) {
      float4 v = *(const float4*)&sheadsH[jj * 4];
      p0a = fmaf(v.x, lk0[4 * jj + 0], p0a); p1a = fmaf(v.x, lk1[4 * jj + 0], p1a);
      p0a = fmaf(v.y, lk0[4 * jj + 1], p0a); p1a = fmaf(v.y, lk1[4 * jj + 1], p1a);
      p0a = fmaf(v.z, lk0[4 * jj + 2], p0a); p1a = fmaf(v.z, lk1[4 * jj + 2], p1a);
      p0a = fmaf(v.w, lk0[4 * jj + 3], p0a); p1a = fmaf(v.w, lk1[4 * jj + 3], p1a);
    }
#pragma unroll
    for (int jj = 2; jj < 4; ++jj) {
      float4 v = *(const float4*)&sheadsH[jj * 4];
      p0b = fmaf(v.x, lk0[4 * jj + 0], p0b); p1b = fmaf(v.x, lk1[4 * jj + 0], p1b);
      p0b = fmaf(v.y, lk0[4 * jj + 1], p0b); p1b = fmaf(v.y, lk1[4 * jj + 1], p1b);
      p0b = fmaf(v.z, lk0[4 * jj + 2], p0b); p1b = fmaf(v.z, lk1[4 * jj + 2], p1b);
      p0b = fmaf(v.w, lk0[4 * jj + 3], p0b); p1b = fmaf(v.w, lk1[4 * jj + 3], p1b);
    }
    if (act) {
      spartB[par * 800 + h * 100 + r0] = p0a + p0b;
      spartB[par * 800 + h * 100 + r1] = p1a + p1b;
    }
    __syncthreads();  // THE barrier

    // (g) final logits: pairwise sum of 8 wave-partials, tanh-clip, mask
    const float* sp = spartB + par * 800;
    float t00 = sp[0 * 100 + r0] + sp[1 * 100 + r0];
    float t01 = sp[2 * 100 + r0] + sp[3 * 100 + r0];
    float t02 = sp[4 * 100 + r0] + sp[5 * 100 + r0];
    float t03 = sp[6 * 100 + r0] + sp[7 * 100 + r0];
    float u00 = sp[0 * 100 + r1] + sp[1 * 100 + r1];
    float u01 = sp[2 * 100 + r1] + sp[3 * 100 + r1];
    float u02 = sp[4 * 100 + r1] + sp[5 * 100 + r1];
    float u03 = sp[6 * 100 + r1] + sp[7 * 100 + r1];
    float s0 = (t00 + t01) + (t02 + t03);
    float s1 = (u00 + u01) + (u02 + u03);
    float l0 = (act && !m0f) ? 10.0f * tanhf(s0) : NEG_INF;
    float l1 = (act && !m1f) ? 10.0f * tanhf(s1) : NEG_INF;

    // (h) combined argmax butterfly (its max IS the softmax max), then LSE
    float bv; int bi;
    if (l1 > l0) { bv = l1; bi = r1; } else { bv = l0; bi = act ? r0 : 1000; }
#pragma unroll
    for (int off = 1; off < 64; off <<= 1) {
      float ov = __shfl_xor(bv, off);
      int oi = __shfl_xor(bi, off);
      if (ov > bv || (ov == bv && oi < bi)) { bv = ov; bi = oi; }
    }
    const int sel = bi;       // identical in every lane
    const float mx2 = bv;     // == max over all logits
    float z = expf(l0 - mx2) + expf(l1 - mx2);
#pragma unroll
    for (int off = 1; off < 64; off <<= 1) z += __shfl_xor(z, off);
    float lsum = logf(z);

    // (i) outputs (wave 0 only)
    if (h == 0) {
      if (l == 0) out_pi[b * 100 + t] = (float)sel;
      if (act) {
        out_logp[lpbase + (size_t)t * 100 + r0] = (l0 - mx2) - lsum;
        out_logp[lpbase + (size_t)t * 100 + r1] = (l1 - mx2) - lsum;
      }
    }

    // (j) t==0: fold F = 0.25*emb[first]@W_step_top into ctx
    if (t == 0) {
      const float* erow = embB + (size_t)sel * 128;
      float fa = 0.f;
      for (int i = 0; i < 32; ++i) {
        int e = qg * 32 + i;
        fa = fmaf(erow[e], W_step[(size_t)e * 128 + h * 16 + dp], fa);
      }
      fa += __shfl_xor(fa, 16);
      fa += __shfl_xor(fa, 32);
      if (l < 16) sbase[h][l] = 0.25f * fa;
      WSYNC();
#pragma unroll
      for (int jj = 0; jj < 4; ++jj) {
        float4 v = *(const float4*)&sbase[h][jj * 4];
        ctx[jj * 4 + 0] += v.x; ctx[jj * 4 + 1] += v.y;
        ctx[jj * 4 + 2] += v.z; ctx[jj * 4 + 3] += v.w;
      }
    }

    // (k) mask update + carry
    m0f = m0f || (act && sel == r0);
    m1f = m1f || (act && sel == r1);
    last = sel;
    par ^= 1;
  }
}

extern "C" void kernel_launch(void* const* d_in, const int* in_sizes, int n_in,
                              void* d_out, int out_size, void* d_ws, size_t ws_size,
                              hipStream_t stream) {
  const float* emb     = (const float*)d_in[0];
  const float* W_node  = (const float*)d_in[1];
  const float* W_fixed = (const float*)d_in[2];
  const float* W_step  = (const float*)d_in[3];
  const float* W_out   = (const float*)d_in[4];
  const float* W_ph    = (const float*)d_in[5];
  float* ws  = (float*)d_ws;
  float* out = (float*)d_out;

  hipLaunchKernelGGL(pre_kernel, dim3(65), dim3(128), 0, stream,
                     W_node, W_out, W_step, W_ph, ws);
  hipLaunchKernelGGL(decode_kernel, dim3(2048), dim3(512), 0, stream,
                     emb, W_node, W_fixed, W_step, ws, out, out + 20480000);
}

// Round 5
// 2715.849 us; speedup vs baseline: 1.4900x; 1.1517x over previous
//
#include <hip/hip_runtime.h>
#include <math.h>

#define NEG_INF (-1e9f)
#define WSYNC() asm volatile("s_waitcnt lgkmcnt(0)" ::: "memory")

// ---------------------------------------------------------------------------
// pre_kernel: builds into ws
//   ws[0 .. 16383]   : Wc[e][d] = (1/sqrt(128)) * sum_j W_node[e,256+j]*W_out[d,j]
//   ws[16384..16511] : qp[d]    = sum_i W_placeholder[i]*W_step[i,d]
// ---------------------------------------------------------------------------
__global__ __launch_bounds__(128) void pre_kernel(
    const float* __restrict__ W_node, const float* __restrict__ W_out,
    const float* __restrict__ W_step, const float* __restrict__ W_ph,
    float* __restrict__ ws) {
  const int bi = blockIdx.x;
  const int tid = threadIdx.x;
  if (bi < 64) {
    __shared__ float woT[64][133];
    float acc0 = 0.f, acc1 = 0.f;
    const int e0 = bi * 2, e1 = e0 + 1;
    for (int ch = 0; ch < 2; ++ch) {
      const int j0 = ch * 64;
      for (int it = 0; it < 64; ++it) {
        int idx = tid + it * 128;
        int jj = idx & 63, ds = idx >> 6;
        woT[jj][ds] = W_out[ds * 128 + j0 + jj];
      }
      __syncthreads();
      for (int jj = 0; jj < 64; ++jj) {
        int j = j0 + jj;
        float a0 = W_node[e0 * 384 + 256 + j];
        float a1 = W_node[e1 * 384 + 256 + j];
        float bb = woT[jj][tid];
        acc0 = fmaf(a0, bb, acc0);
        acc1 = fmaf(a1, bb, acc1);
      }
      __syncthreads();
    }
    const float rs = 0.08838834764831845f;  // 1/sqrt(128)
    ws[e0 * 128 + tid] = acc0 * rs;
    ws[e1 * 128 + tid] = acc1 * rs;
  } else {
    float acc = 0.f;
    for (int i = 0; i < 256; ++i) acc = fmaf(W_ph[i], W_step[i * 128 + tid], acc);
    ws[16384 + tid] = acc;
  }
}

// ---------------------------------------------------------------------------
// decode_kernel: one block (512 thr = 8 waves) per batch row.
// wave h = head h; lane l owns rows {l, l+50} (l<50 active).
//
// LDS ~116 KB on purpose: the AMDGPU backend derives its VGPR cap from the
// LDS-implied occupancy. At 63.5 KB it targeted 2 WGs/CU -> 128-VGPR cap ->
// scratch spills (rounds 3/4: +0.3-0.5 GB HBM traffic, per-step L2-latency
// reloads). At 116 KB it targets 1 WG/CU (which is all we ever got anyway,
// occupancy ~24%) -> 256-VGPR budget -> no spills.
//
// semb (emb, chunk-XOR-swizzled) stays live the whole kernel; sE is separate.
// sE rows hold ctx + 0.25*E[n] (F added in-place after t==0), so the loop
// reads the query directly. Init is 3 sequential passes (gv -> gvt transpose;
// Ea -> sE; gk/lk kept in regs) to cap register pressure ~120.
// One __syncthreads per decode step.
// ---------------------------------------------------------------------------
__global__ __launch_bounds__(512) void decode_kernel(
    const float* __restrict__ emb,      // [2048][100][128]
    const float* __restrict__ W_node,   // [128][384]
    const float* __restrict__ W_fixed,  // [128][128]
    const float* __restrict__ W_step,   // [256][128]
    const float* __restrict__ ws,       // Wc + qp
    float* __restrict__ out_logp,       // [2048][100][100]
    float* __restrict__ out_pi) {       // [2048][100] (as float)
  const int b = blockIdx.x;
  const int tid = threadIdx.x;
  const int h = tid >> 6;       // wave == head
  const int l = tid & 63;       // lane
  const int dp = l & 15;        // d' within head slice
  const int qg = l >> 4;        // row-quarter group 0..3
  const bool act = (l < 50);
  const int r0 = act ? l : 0;
  const int r1 = act ? l + 50 : 0;
  const int qq0 = (l < 25) ? 0 : 1;   // attn quarter of r0
  const int ii0 = l - qq0 * 25;       // index within quarter

  __shared__ __align__(16) float semb[100][128];   // 51200 B, swizzled, permanent
  __shared__ __align__(16) float sE[8][100][16];   // 51200 B, ctx(+F)+0.25*E
  __shared__ __align__(16) float pool[3200];       // 12800 B multi-use
  __shared__ float smean[128];
  __shared__ __align__(16) float sbase[8][16];

  const float* embB = emb + (size_t)b * 12800;
  float* sembf = &semb[0][0];
  float4* semb4 = (float4*)sembf;

  // ---- stage emb into LDS, chunk-swizzled: phys_chunk = c ^ (n&7) ----
  for (int it = 0; it < 7; ++it) {
    int qi = tid + it * 512;
    if (qi < 3200) {
      int n = qi >> 5, c = qi & 31;
      semb4[n * 32 + (c ^ (n & 7))] = ((const float4*)embB)[qi];
    }
  }
  __syncthreads();

  // ---- graph mean (pool as scratch) ----
  {
    int d = tid & 127, q2 = tid >> 7;
    int ch = d >> 2, cl = d & 3;
    float p = 0.f;
    for (int n = q2 * 25; n < q2 * 25 + 25; ++n)
      p += sembf[n * 128 + ((ch ^ (n & 7)) << 2) + cl];
    pool[q2 * 128 + d] = p;
  }
  __syncthreads();
  if (tid < 128)
    smean[tid] = (pool[tid] + pool[128 + tid] + pool[256 + tid] + pool[384 + tid]) * 0.01f;
  __syncthreads();

  // ---- ctx[16] = 0.25 * (mean @ W_fixed) head-slice, replicated per lane ----
  float ctx[16];
  {
    float a = 0.f;
    for (int i = 0; i < 32; ++i) {
      int e = qg * 32 + i;
      a = fmaf(smean[e], W_fixed[e * 128 + h * 16 + dp], a);
    }
    a += __shfl_xor(a, 16);
    a += __shfl_xor(a, 32);
    if (l < 16) sbase[h][l] = 0.25f * a;
    WSYNC();
#pragma unroll
    for (int jj = 0; jj < 4; ++jj) {
      float4 v = *(const float4*)&sbase[h][jj * 4];
      ctx[jj * 4 + 0] = v.x; ctx[jj * 4 + 1] = v.y;
      ctx[jj * 4 + 2] = v.z; ctx[jj * 4 + 3] = v.w;
    }
  }

  // ================= Pass A: gv rows -> transpose -> gvt[25] =================
  float gvt[25];
  {
    float gv0[16], gv1[16];
#pragma unroll
    for (int j = 0; j < 16; ++j) gv0[j] = gv1[j] = 0.f;
#pragma unroll 2
    for (int e4 = 0; e4 < 32; ++e4) {
      float4 a0 = semb4[r0 * 32 + (e4 ^ (r0 & 7))];
      float4 a1 = semb4[r1 * 32 + (e4 ^ (r1 & 7))];
      float em0[4] = {a0.x, a0.y, a0.z, a0.w};
      float em1[4] = {a1.x, a1.y, a1.z, a1.w};
#pragma unroll
      for (int eo = 0; eo < 4; ++eo) {
        const int e = e4 * 4 + eo;
        const float ev0 = em0[eo], ev1 = em1[eo];
        const float* wv = &W_node[e * 384 + 128 + h * 16];
#pragma unroll
        for (int j = 0; j < 16; ++j) {
          float wvj = wv[j];
          gv0[j] = fmaf(ev0, wvj, gv0[j]);
          gv1[j] = fmaf(ev1, wvj, gv1[j]);
        }
      }
    }
    // transpose via pool (wave-private slice [h*400 .. h*400+399])
    float* gvtmp = pool;
#pragma unroll 1
    for (int pass = 0; pass < 4; ++pass) {
      WSYNC();
      if (act) {
        if (qq0 == pass) {
          float4* w = (float4*)(gvtmp + (h * 25 + ii0) * 16);
#pragma unroll
          for (int jj = 0; jj < 4; ++jj)
            w[jj] = make_float4(gv0[jj * 4], gv0[jj * 4 + 1], gv0[jj * 4 + 2], gv0[jj * 4 + 3]);
        }
        if (qq0 + 2 == pass) {
          float4* w = (float4*)(gvtmp + (h * 25 + ii0) * 16);
#pragma unroll
          for (int jj = 0; jj < 4; ++jj)
            w[jj] = make_float4(gv1[jj * 4], gv1[jj * 4 + 1], gv1[jj * 4 + 2], gv1[jj * 4 + 3]);
        }
      }
      WSYNC();
      if (qg == pass) {
#pragma unroll
        for (int i = 0; i < 25; ++i) gvt[i] = gvtmp[(h * 25 + i) * 16 + dp];
      }
    }
  }
  __syncthreads();  // pool handoff: gvtmp done, loop layout begins

  // pool layout (floats): sattn  = pool + h*112 (4 quarters x 28)
  //                       sheads = pool + 896 + h*16
  //                       spart  = pool + 1024 + par*800 + h*100 + n
  //                       sqp    = pool + 2624 + h*16   (ctx + 0.25*qp)
  float* sattnH = pool + h * 112;
  float* sheadsH = pool + 896 + h * 16;
  float* spartB = pool + 1024;
  float* sqpH = pool + 2624 + h * 16;

  // ================= Pass B: Ea rows -> sE = ctx + 0.25*E ====================
  {
    float Ea0[16], Ea1[16];
#pragma unroll
    for (int j = 0; j < 16; ++j) Ea0[j] = Ea1[j] = 0.f;
#pragma unroll 2
    for (int e4 = 0; e4 < 32; ++e4) {
      float4 a0 = semb4[r0 * 32 + (e4 ^ (r0 & 7))];
      float4 a1 = semb4[r1 * 32 + (e4 ^ (r1 & 7))];
      float em0[4] = {a0.x, a0.y, a0.z, a0.w};
      float em1[4] = {a1.x, a1.y, a1.z, a1.w};
#pragma unroll
      for (int eo = 0; eo < 4; ++eo) {
        const int e = e4 * 4 + eo;
        const float ev0 = em0[eo], ev1 = em1[eo];
        const float* wE = &W_step[(size_t)(128 + e) * 128 + h * 16];
#pragma unroll
        for (int j = 0; j < 16; ++j) {
          float wEj = wE[j];
          Ea0[j] = fmaf(ev0, wEj, Ea0[j]);
          Ea1[j] = fmaf(ev1, wEj, Ea1[j]);
        }
      }
    }
    if (act) {
      float4* d0 = (float4*)&sE[h][r0][0];
      float4* d1 = (float4*)&sE[h][r1][0];
#pragma unroll
      for (int jj = 0; jj < 4; ++jj) {
        d0[jj] = make_float4(ctx[jj * 4 + 0] + 0.25f * Ea0[jj * 4 + 0],
                             ctx[jj * 4 + 1] + 0.25f * Ea0[jj * 4 + 1],
                             ctx[jj * 4 + 2] + 0.25f * Ea0[jj * 4 + 2],
                             ctx[jj * 4 + 3] + 0.25f * Ea0[jj * 4 + 3]);
        d1[jj] = make_float4(ctx[jj * 4 + 0] + 0.25f * Ea1[jj * 4 + 0],
                             ctx[jj * 4 + 1] + 0.25f * Ea1[jj * 4 + 1],
                             ctx[jj * 4 + 2] + 0.25f * Ea1[jj * 4 + 2],
                             ctx[jj * 4 + 3] + 0.25f * Ea1[jj * 4 + 3]);
      }
    }
    if (l == 0) {
      float4* dq = (float4*)sqpH;
#pragma unroll
      for (int jj = 0; jj < 4; ++jj) {
        float4 w = *(const float4*)&ws[16384 + h * 16 + jj * 4];
        dq[jj] = make_float4(ctx[jj * 4 + 0] + 0.25f * w.x,
                             ctx[jj * 4 + 1] + 0.25f * w.y,
                             ctx[jj * 4 + 2] + 0.25f * w.z,
                             ctx[jj * 4 + 3] + 0.25f * w.w);
      }
    }
  }

  // ================= Pass C: gk, lk' rows (loop-resident) ====================
  float gk0[16], gk1[16], lk0[16], lk1[16];
#pragma unroll
  for (int j = 0; j < 16; ++j) gk0[j] = gk1[j] = lk0[j] = lk1[j] = 0.f;
#pragma unroll 2
  for (int e4 = 0; e4 < 32; ++e4) {
    float4 a0 = semb4[r0 * 32 + (e4 ^ (r0 & 7))];
    float4 a1 = semb4[r1 * 32 + (e4 ^ (r1 & 7))];
    float em0[4] = {a0.x, a0.y, a0.z, a0.w};
    float em1[4] = {a1.x, a1.y, a1.z, a1.w};
#pragma unroll
    for (int eo = 0; eo < 4; ++eo) {
      const int e = e4 * 4 + eo;
      const float ev0 = em0[eo], ev1 = em1[eo];
      const float* wk = &W_node[e * 384 + h * 16];
      const float* wl = &ws[e * 128 + h * 16];
#pragma unroll
      for (int j = 0; j < 16; ++j) {
        float wkj = wk[j], wlj = wl[j];
        gk0[j] = fmaf(ev0, wkj, gk0[j]); gk1[j] = fmaf(ev1, wkj, gk1[j]);
        lk0[j] = fmaf(ev0, wlj, lk0[j]); lk1[j] = fmaf(ev1, wlj, lk1[j]);
      }
    }
  }
  __syncthreads();  // sE/sqp visible; pool loop-layout stable

  // ---- decode loop ----
  bool m0f = false, m1f = false;
  int last = 0;
  int par = 0;
  const size_t lpbase = (size_t)b * 10000;

#pragma unroll 1
  for (int t = 0; t < 100; ++t) {
    // (a,b) query (pre-folded: ctx[+F]+0.25E) + compat for my two rows
    const float* epf = (t == 0) ? sqpH : &sE[h][last][0];
    const float4* ep = (const float4*)epf;
    float c0a = 0.f, c0b = 0.f, c1a = 0.f, c1b = 0.f;
#pragma unroll
    for (int jj = 0; jj < 2; ++jj) {
      float4 v = ep[jj];
      c0a = fmaf(v.x, gk0[4 * jj + 0], c0a); c1a = fmaf(v.x, gk1[4 * jj + 0], c1a);
      c0a = fmaf(v.y, gk0[4 * jj + 1], c0a); c1a = fmaf(v.y, gk1[4 * jj + 1], c1a);
      c0a = fmaf(v.z, gk0[4 * jj + 2], c0a); c1a = fmaf(v.z, gk1[4 * jj + 2], c1a);
      c0a = fmaf(v.w, gk0[4 * jj + 3], c0a); c1a = fmaf(v.w, gk1[4 * jj + 3], c1a);
    }
#pragma unroll
    for (int jj = 2; jj < 4; ++jj) {
      float4 v = ep[jj];
      c0b = fmaf(v.x, gk0[4 * jj + 0], c0b); c1b = fmaf(v.x, gk1[4 * jj + 0], c1b);
      c0b = fmaf(v.y, gk0[4 * jj + 1], c0b); c1b = fmaf(v.y, gk1[4 * jj + 1], c1b);
      c0b = fmaf(v.z, gk0[4 * jj + 2], c0b); c1b = fmaf(v.z, gk1[4 * jj + 2], c1b);
      c0b = fmaf(v.w, gk0[4 * jj + 3], c0b); c1b = fmaf(v.w, gk1[4 * jj + 3], c1b);
    }
    float v0 = (act && !m0f) ? (c0a + c0b) : NEG_INF;
    float v1 = (act && !m1f) ? (c1a + c1b) : NEG_INF;

    // (c) in-wave softmax over 100 rows
    float mx = fmaxf(v0, v1);
#pragma unroll
    for (int off = 1; off < 64; off <<= 1) mx = fmaxf(mx, __shfl_xor(mx, off));
    float e0 = expf(v0 - mx), e1 = expf(v1 - mx);
    float s = e0 + e1;
#pragma unroll
    for (int off = 1; off < 64; off <<= 1) s += __shfl_xor(s, off);
    float a0 = e0 / s, a1 = e1 / s;

    // (d) attn -> wave-private LDS
    if (act) {
      sattnH[qq0 * 28 + ii0] = a0;
      sattnH[(qq0 + 2) * 28 + ii0] = a1;
    }
    WSYNC();

    // (e) heads: lane (dp,qg) accumulates its 25 rows
    {
      const float* ap = sattnH + qg * 28;
      float ha = 0.f, hb = 0.f;
#pragma unroll
      for (int ii = 0; ii < 6; ++ii) {
        float4 v = ((const float4*)ap)[ii];
        ha = fmaf(v.x, gvt[4 * ii + 0], ha);
        hb = fmaf(v.y, gvt[4 * ii + 1], hb);
        ha = fmaf(v.z, gvt[4 * ii + 2], ha);
        hb = fmaf(v.w, gvt[4 * ii + 3], hb);
      }
      ha = fmaf(ap[24], gvt[24], ha);
      float hacc = ha + hb;
      hacc += __shfl_xor(hacc, 16);
      hacc += __shfl_xor(hacc, 32);
      if (l < 16) sheadsH[l] = hacc;
    }
    WSYNC();

    // (f) logits partial for my rows over this wave's 16 d
    float p0a = 0.f, p0b = 0.f, p1a = 0.f, p1b = 0.f;
#pragma unroll
    for (int jj = 0; jj < 2; ++jj) {
      float4 v = *(const float4*)&sheadsH[jj * 4];
      p0a = fmaf(v.x, lk0[4 * jj + 0], p0a); p1a = fmaf(v.x, lk1[4 * jj + 0], p1a);
      p0a = fmaf(v.y, lk0[4 * jj + 1], p0a); p1a = fmaf(v.y, lk1[4 * jj + 1], p1a);
      p0a = fmaf(v.z, lk0[4 * jj + 2], p0a); p1a = fmaf(v.z, lk1[4 * jj + 2], p1a);
      p0a = fmaf(v.w, lk0[4 * jj + 3], p0a); p1a = fmaf(v.w, lk1[4 * jj + 3], p1a);
    }
#pragma unroll
    for (int jj = 2; jj < 4; ++jj) {
      float4 v = *(const float4*)&sheadsH[jj * 4];
      p0b = fmaf(v.x, lk0[4 * jj + 0], p0b); p1b = fmaf(v.x, lk1[4 * jj + 0], p1b);
      p0b = fmaf(v.y, lk0[4 * jj + 1], p0b); p1b = fmaf(v.y, lk1[4 * jj + 1], p1b);
      p0b = fmaf(v.z, lk0[4 * jj + 2], p0b); p1b = fmaf(v.z, lk1[4 * jj + 2], p1b);
      p0b = fmaf(v.w, lk0[4 * jj + 3], p0b); p1b = fmaf(v.w, lk1[4 * jj + 3], p1b);
    }
    if (act) {
      spartB[par * 800 + h * 100 + r0] = p0a + p0b;
      spartB[par * 800 + h * 100 + r1] = p1a + p1b;
    }
    __syncthreads();  // THE barrier

    // (g) final logits: pairwise sum of 8 wave-partials, tanh-clip, mask
    const float* sp = spartB + par * 800;
    float t00 = sp[0 * 100 + r0] + sp[1 * 100 + r0];
    float t01 = sp[2 * 100 + r0] + sp[3 * 100 + r0];
    float t02 = sp[4 * 100 + r0] + sp[5 * 100 + r0];
    float t03 = sp[6 * 100 + r0] + sp[7 * 100 + r0];
    float u00 = sp[0 * 100 + r1] + sp[1 * 100 + r1];
    float u01 = sp[2 * 100 + r1] + sp[3 * 100 + r1];
    float u02 = sp[4 * 100 + r1] + sp[5 * 100 + r1];
    float u03 = sp[6 * 100 + r1] + sp[7 * 100 + r1];
    float s0 = (t00 + t01) + (t02 + t03);
    float s1 = (u00 + u01) + (u02 + u03);
    float l0 = (act && !m0f) ? 10.0f * tanhf(s0) : NEG_INF;
    float l1 = (act && !m1f) ? 10.0f * tanhf(s1) : NEG_INF;

    // (h) argmax butterfly || direct log-sum-exp (logits <= 10, so Z = sum e^l
    //     is safe: Z <= 100*e^10 ~ 2.2e6; masked e^-1e9 = 0). The two 6-level
    //     butterflies are independent -> ILP instead of serialization.
    float bv; int bi;
    if (l1 > l0) { bv = l1; bi = r1; } else { bv = l0; bi = act ? r0 : 1000; }
    float z = expf(l0) + expf(l1);
#pragma unroll
    for (int off = 1; off < 64; off <<= 1) {
      float ov = __shfl_xor(bv, off);
      int oi = __shfl_xor(bi, off);
      z += __shfl_xor(z, off);
      if (ov > bv || (ov == bv && oi < bi)) { bv = ov; bi = oi; }
    }
    const int sel = bi;  // identical in every lane
    float lsum = logf(z);

    // (i) outputs (wave 0 only)
    if (h == 0) {
      if (l == 0) out_pi[b * 100 + t] = (float)sel;
      if (act) {
        out_logp[lpbase + (size_t)t * 100 + r0] = l0 - lsum;
        out_logp[lpbase + (size_t)t * 100 + r1] = l1 - lsum;
      }
    }

    // (j) t==0: fold F = 0.25*emb[first]@W_step_top into ALL sE rows + done
    if (t == 0) {
      float fa = 0.f;
      for (int i = 0; i < 32; ++i) {
        int e = qg * 32 + i;
        float ev = sembf[sel * 128 + (((e >> 2) ^ (sel & 7)) << 2) + (e & 3)];
        fa = fmaf(ev, W_step[(size_t)e * 128 + h * 16 + dp], fa);
      }
      fa += __shfl_xor(fa, 16);
      fa += __shfl_xor(fa, 32);
      if (l < 16) sbase[h][l] = 0.25f * fa;
      WSYNC();
      if (act) {
        float4* p0 = (float4*)&sE[h][r0][0];
        float4* p1 = (float4*)&sE[h][r1][0];
#pragma unroll
        for (int jj = 0; jj < 4; ++jj) {
          float4 f = *(const float4*)&sbase[h][jj * 4];
          float4 c0 = p0[jj], c1 = p1[jj];
          c0.x += f.x; c0.y += f.y; c0.z += f.z; c0.w += f.w;
          c1.x += f.x; c1.y += f.y; c1.z += f.z; c1.w += f.w;
          p0[jj] = c0; p1[jj] = c1;
        }
      }
      WSYNC();
    }

    // (k) mask update + carry
    m0f = m0f || (act && sel == r0);
    m1f = m1f || (act && sel == r1);
    last = sel;
    par ^= 1;
  }
}

extern "C" void kernel_launch(void* const* d_in, const int* in_sizes, int n_in,
                              void* d_out, int out_size, void* d_ws, size_t ws_size,
                              hipStream_t stream) {
  const float* emb     = (const float*)d_in[0];
  const float* W_node  = (const float*)d_in[1];
  const float* W_fixed = (const float*)d_in[2];
  const float* W_step  = (const float*)d_in[3];
  const float* W_out   = (const float*)d_in[4];
  const float* W_ph    = (const float*)d_in[5];
  float* ws  = (float*)d_ws;
  float* out = (float*)d_out;

  hipLaunchKernelGGL(pre_kernel, dim3(65), dim3(128), 0, stream,
                     W_node, W_out, W_step, W_ph, ws);
  hipLaunchKernelGGL(decode_kernel, dim3(2048), dim3(512), 0, stream,
                     emb, W_node, W_fixed, W_step, ws, out, out + 20480000);
}

// Round 6
// 2706.912 us; speedup vs baseline: 1.4949x; 1.0033x over previous
//
#include <hip/hip_runtime.h>
#include <math.h>

#define NEG_INF (-1e9f)
#define WSYNC() asm volatile("s_waitcnt lgkmcnt(0)" ::: "memory")

// ---------------------------------------------------------------------------
// pre_kernel: builds into ws
//   ws[0 .. 16383]   : Wc[e][d] = (1/sqrt(128)) * sum_j W_node[e,256+j]*W_out[d,j]
//   ws[16384..16511] : qp[d]    = sum_i W_placeholder[i]*W_step[i,d]
// ---------------------------------------------------------------------------
__global__ __launch_bounds__(128) void pre_kernel(
    const float* __restrict__ W_node, const float* __restrict__ W_out,
    const float* __restrict__ W_step, const float* __restrict__ W_ph,
    float* __restrict__ ws) {
  const int bi = blockIdx.x;
  const int tid = threadIdx.x;
  if (bi < 64) {
    __shared__ float woT[64][133];
    float acc0 = 0.f, acc1 = 0.f;
    const int e0 = bi * 2, e1 = e0 + 1;
    for (int ch = 0; ch < 2; ++ch) {
      const int j0 = ch * 64;
      for (int it = 0; it < 64; ++it) {
        int idx = tid + it * 128;
        int jj = idx & 63, ds = idx >> 6;
        woT[jj][ds] = W_out[ds * 128 + j0 + jj];
      }
      __syncthreads();
      for (int jj = 0; jj < 64; ++jj) {
        int j = j0 + jj;
        float a0 = W_node[e0 * 384 + 256 + j];
        float a1 = W_node[e1 * 384 + 256 + j];
        float bb = woT[jj][tid];
        acc0 = fmaf(a0, bb, acc0);
        acc1 = fmaf(a1, bb, acc1);
      }
      __syncthreads();
    }
    const float rs = 0.08838834764831845f;  // 1/sqrt(128)
    ws[e0 * 128 + tid] = acc0 * rs;
    ws[e1 * 128 + tid] = acc1 * rs;
  } else {
    float acc = 0.f;
    for (int i = 0; i < 256; ++i) acc = fmaf(W_ph[i], W_step[i * 128 + tid], acc);
    ws[16384 + tid] = acc;
  }
}

// ---------------------------------------------------------------------------
// decode_kernel: one block (512 thr = 8 waves) per batch row.
// wave h = head h; lane l owns rows {l, l+50} (l<50 active).
//
// amdgpu_waves_per_eu(2,2): rounds 3-5 all came back with VGPR_Count=128 and
// ~300 MB/dispatch of scratch-spill HBM writes -- the backend's occupancy
// heuristic targets 4 waves/EU (cap 128) REGARDLESS of LDS size or the
// launch_bounds minimum, and spills to get there. Pinning waves/EU to exactly
// 2 (= our 8-wave block at 1 WG/CU, which is all we ever got: occupancy ~24%)
// raises the allocator budget to 256 VGPRs -> live set (~120) fits, no
// scratch. Scratch allocation per-wave is also the suspected blocker for a
// 2nd co-resident block in the 63.5 KB round-4 config.
//
// semb (emb, chunk-XOR-swizzled) stays live the whole kernel; sE is separate.
// sE rows hold ctx + 0.25*E[n] (F added in-place after t==0), so the loop
// reads the query directly. Init is 3 sequential passes (gv -> gvt transpose;
// Ea -> sE; gk/lk kept in regs) to cap register pressure.
// One __syncthreads per decode step.
// ---------------------------------------------------------------------------
__global__ __launch_bounds__(512)
__attribute__((amdgpu_waves_per_eu(2, 2)))
void decode_kernel(
    const float* __restrict__ emb,      // [2048][100][128]
    const float* __restrict__ W_node,   // [128][384]
    const float* __restrict__ W_fixed,  // [128][128]
    const float* __restrict__ W_step,   // [256][128]
    const float* __restrict__ ws,       // Wc + qp
    float* __restrict__ out_logp,       // [2048][100][100]
    float* __restrict__ out_pi) {       // [2048][100] (as float)
  const int b = blockIdx.x;
  const int tid = threadIdx.x;
  const int h = tid >> 6;       // wave == head
  const int l = tid & 63;       // lane
  const int dp = l & 15;        // d' within head slice
  const int qg = l >> 4;        // row-quarter group 0..3
  const bool act = (l < 50);
  const int r0 = act ? l : 0;
  const int r1 = act ? l + 50 : 0;
  const int qq0 = (l < 25) ? 0 : 1;   // attn quarter of r0
  const int ii0 = l - qq0 * 25;       // index within quarter

  __shared__ __align__(16) float semb[100][128];   // 51200 B, swizzled, permanent
  __shared__ __align__(16) float sE[8][100][16];   // 51200 B, ctx(+F)+0.25*E
  __shared__ __align__(16) float pool[3200];       // 12800 B multi-use
  __shared__ float smean[128];
  __shared__ __align__(16) float sbase[8][16];

  const float* embB = emb + (size_t)b * 12800;
  float* sembf = &semb[0][0];
  float4* semb4 = (float4*)sembf;

  // ---- stage emb into LDS, chunk-swizzled: phys_chunk = c ^ (n&7) ----
  for (int it = 0; it < 7; ++it) {
    int qi = tid + it * 512;
    if (qi < 3200) {
      int n = qi >> 5, c = qi & 31;
      semb4[n * 32 + (c ^ (n & 7))] = ((const float4*)embB)[qi];
    }
  }
  __syncthreads();

  // ---- graph mean (pool as scratch) ----
  {
    int d = tid & 127, q2 = tid >> 7;
    int ch = d >> 2, cl = d & 3;
    float p = 0.f;
    for (int n = q2 * 25; n < q2 * 25 + 25; ++n)
      p += sembf[n * 128 + ((ch ^ (n & 7)) << 2) + cl];
    pool[q2 * 128 + d] = p;
  }
  __syncthreads();
  if (tid < 128)
    smean[tid] = (pool[tid] + pool[128 + tid] + pool[256 + tid] + pool[384 + tid]) * 0.01f;
  __syncthreads();

  // ---- ctx[16] = 0.25 * (mean @ W_fixed) head-slice, replicated per lane ----
  float ctx[16];
  {
    float a = 0.f;
    for (int i = 0; i < 32; ++i) {
      int e = qg * 32 + i;
      a = fmaf(smean[e], W_fixed[e * 128 + h * 16 + dp], a);
    }
    a += __shfl_xor(a, 16);
    a += __shfl_xor(a, 32);
    if (l < 16) sbase[h][l] = 0.25f * a;
    WSYNC();
#pragma unroll
    for (int jj = 0; jj < 4; ++jj) {
      float4 v = *(const float4*)&sbase[h][jj * 4];
      ctx[jj * 4 + 0] = v.x; ctx[jj * 4 + 1] = v.y;
      ctx[jj * 4 + 2] = v.z; ctx[jj * 4 + 3] = v.w;
    }
  }

  // ================= Pass A: gv rows -> transpose -> gvt[25] =================
  float gvt[25];
  {
    float gv0[16], gv1[16];
#pragma unroll
    for (int j = 0; j < 16; ++j) gv0[j] = gv1[j] = 0.f;
#pragma unroll 2
    for (int e4 = 0; e4 < 32; ++e4) {
      float4 a0 = semb4[r0 * 32 + (e4 ^ (r0 & 7))];
      float4 a1 = semb4[r1 * 32 + (e4 ^ (r1 & 7))];
      float em0[4] = {a0.x, a0.y, a0.z, a0.w};
      float em1[4] = {a1.x, a1.y, a1.z, a1.w};
#pragma unroll
      for (int eo = 0; eo < 4; ++eo) {
        const int e = e4 * 4 + eo;
        const float ev0 = em0[eo], ev1 = em1[eo];
        const float* wv = &W_node[e * 384 + 128 + h * 16];
#pragma unroll
        for (int j = 0; j < 16; ++j) {
          float wvj = wv[j];
          gv0[j] = fmaf(ev0, wvj, gv0[j]);
          gv1[j] = fmaf(ev1, wvj, gv1[j]);
        }
      }
    }
    // transpose via pool (wave-private slice [h*400 .. h*400+399])
    float* gvtmp = pool;
#pragma unroll 1
    for (int pass = 0; pass < 4; ++pass) {
      WSYNC();
      if (act) {
        if (qq0 == pass) {
          float4* w = (float4*)(gvtmp + (h * 25 + ii0) * 16);
#pragma unroll
          for (int jj = 0; jj < 4; ++jj)
            w[jj] = make_float4(gv0[jj * 4], gv0[jj * 4 + 1], gv0[jj * 4 + 2], gv0[jj * 4 + 3]);
        }
        if (qq0 + 2 == pass) {
          float4* w = (float4*)(gvtmp + (h * 25 + ii0) * 16);
#pragma unroll
          for (int jj = 0; jj < 4; ++jj)
            w[jj] = make_float4(gv1[jj * 4], gv1[jj * 4 + 1], gv1[jj * 4 + 2], gv1[jj * 4 + 3]);
        }
      }
      WSYNC();
      if (qg == pass) {
#pragma unroll
        for (int i = 0; i < 25; ++i) gvt[i] = gvtmp[(h * 25 + i) * 16 + dp];
      }
    }
  }
  __syncthreads();  // pool handoff: gvtmp done, loop layout begins

  // pool layout (floats): sattn  = pool + h*112 (4 quarters x 28)
  //                       sheads = pool + 896 + h*16
  //                       spart  = pool + 1024 + par*800 + h*100 + n
  //                       sqp    = pool + 2624 + h*16   (ctx + 0.25*qp)
  float* sattnH = pool + h * 112;
  float* sheadsH = pool + 896 + h * 16;
  float* spartB = pool + 1024;
  float* sqpH = pool + 2624 + h * 16;

  // ================= Pass B: Ea rows -> sE = ctx + 0.25*E ====================
  {
    float Ea0[16], Ea1[16];
#pragma unroll
    for (int j = 0; j < 16; ++j) Ea0[j] = Ea1[j] = 0.f;
#pragma unroll 2
    for (int e4 = 0; e4 < 32; ++e4) {
      float4 a0 = semb4[r0 * 32 + (e4 ^ (r0 & 7))];
      float4 a1 = semb4[r1 * 32 + (e4 ^ (r1 & 7))];
      float em0[4] = {a0.x, a0.y, a0.z, a0.w};
      float em1[4] = {a1.x, a1.y, a1.z, a1.w};
#pragma unroll
      for (int eo = 0; eo < 4; ++eo) {
        const int e = e4 * 4 + eo;
        const float ev0 = em0[eo], ev1 = em1[eo];
        const float* wE = &W_step[(size_t)(128 + e) * 128 + h * 16];
#pragma unroll
        for (int j = 0; j < 16; ++j) {
          float wEj = wE[j];
          Ea0[j] = fmaf(ev0, wEj, Ea0[j]);
          Ea1[j] = fmaf(ev1, wEj, Ea1[j]);
        }
      }
    }
    if (act) {
      float4* d0 = (float4*)&sE[h][r0][0];
      float4* d1 = (float4*)&sE[h][r1][0];
#pragma unroll
      for (int jj = 0; jj < 4; ++jj) {
        d0[jj] = make_float4(ctx[jj * 4 + 0] + 0.25f * Ea0[jj * 4 + 0],
                             ctx[jj * 4 + 1] + 0.25f * Ea0[jj * 4 + 1],
                             ctx[jj * 4 + 2] + 0.25f * Ea0[jj * 4 + 2],
                             ctx[jj * 4 + 3] + 0.25f * Ea0[jj * 4 + 3]);
        d1[jj] = make_float4(ctx[jj * 4 + 0] + 0.25f * Ea1[jj * 4 + 0],
                             ctx[jj * 4 + 1] + 0.25f * Ea1[jj * 4 + 1],
                             ctx[jj * 4 + 2] + 0.25f * Ea1[jj * 4 + 2],
                             ctx[jj * 4 + 3] + 0.25f * Ea1[jj * 4 + 3]);
      }
    }
    if (l == 0) {
      float4* dq = (float4*)sqpH;
#pragma unroll
      for (int jj = 0; jj < 4; ++jj) {
        float4 w = *(const float4*)&ws[16384 + h * 16 + jj * 4];
        dq[jj] = make_float4(ctx[jj * 4 + 0] + 0.25f * w.x,
                             ctx[jj * 4 + 1] + 0.25f * w.y,
                             ctx[jj * 4 + 2] + 0.25f * w.z,
                             ctx[jj * 4 + 3] + 0.25f * w.w);
      }
    }
  }

  // ================= Pass C: gk, lk' rows (loop-resident) ====================
  float gk0[16], gk1[16], lk0[16], lk1[16];
#pragma unroll
  for (int j = 0; j < 16; ++j) gk0[j] = gk1[j] = lk0[j] = lk1[j] = 0.f;
#pragma unroll 2
  for (int e4 = 0; e4 < 32; ++e4) {
    float4 a0 = semb4[r0 * 32 + (e4 ^ (r0 & 7))];
    float4 a1 = semb4[r1 * 32 + (e4 ^ (r1 & 7))];
    float em0[4] = {a0.x, a0.y, a0.z, a0.w};
    float em1[4] = {a1.x, a1.y, a1.z, a1.w};
#pragma unroll
    for (int eo = 0; eo < 4; ++eo) {
      const int e = e4 * 4 + eo;
      const float ev0 = em0[eo], ev1 = em1[eo];
      const float* wk = &W_node[e * 384 + h * 16];
      const float* wl = &ws[e * 128 + h * 16];
#pragma unroll
      for (int j = 0; j < 16; ++j) {
        float wkj = wk[j], wlj = wl[j];
        gk0[j] = fmaf(ev0, wkj, gk0[j]); gk1[j] = fmaf(ev1, wkj, gk1[j]);
        lk0[j] = fmaf(ev0, wlj, lk0[j]); lk1[j] = fmaf(ev1, wlj, lk1[j]);
      }
    }
  }
  __syncthreads();  // sE/sqp visible; pool loop-layout stable

  // ---- decode loop ----
  bool m0f = false, m1f = false;
  int last = 0;
  int par = 0;
  const size_t lpbase = (size_t)b * 10000;

#pragma unroll 1
  for (int t = 0; t < 100; ++t) {
    // (a,b) query (pre-folded: ctx[+F]+0.25E) + compat for my two rows
    const float* epf = (t == 0) ? sqpH : &sE[h][last][0];
    const float4* ep = (const float4*)epf;
    float c0a = 0.f, c0b = 0.f, c1a = 0.f, c1b = 0.f;
#pragma unroll
    for (int jj = 0; jj < 2; ++jj) {
      float4 v = ep[jj];
      c0a = fmaf(v.x, gk0[4 * jj + 0], c0a); c1a = fmaf(v.x, gk1[4 * jj + 0], c1a);
      c0a = fmaf(v.y, gk0[4 * jj + 1], c0a); c1a = fmaf(v.y, gk1[4 * jj + 1], c1a);
      c0a = fmaf(v.z, gk0[4 * jj + 2], c0a); c1a = fmaf(v.z, gk1[4 * jj + 2], c1a);
      c0a = fmaf(v.w, gk0[4 * jj + 3], c0a); c1a = fmaf(v.w, gk1[4 * jj + 3], c1a);
    }
#pragma unroll
    for (int jj = 2; jj < 4; ++jj) {
      float4 v = ep[jj];
      c0b = fmaf(v.x, gk0[4 * jj + 0], c0b); c1b = fmaf(v.x, gk1[4 * jj + 0], c1b);
      c0b = fmaf(v.y, gk0[4 * jj + 1], c0b); c1b = fmaf(v.y, gk1[4 * jj + 1], c1b);
      c0b = fmaf(v.z, gk0[4 * jj + 2], c0b); c1b = fmaf(v.z, gk1[4 * jj + 2], c1b);
      c0b = fmaf(v.w, gk0[4 * jj + 3], c0b); c1b = fmaf(v.w, gk1[4 * jj + 3], c1b);
    }
    float v0 = (act && !m0f) ? (c0a + c0b) : NEG_INF;
    float v1 = (act && !m1f) ? (c1a + c1b) : NEG_INF;

    // (c) in-wave softmax over 100 rows
    float mx = fmaxf(v0, v1);
#pragma unroll
    for (int off = 1; off < 64; off <<= 1) mx = fmaxf(mx, __shfl_xor(mx, off));
    float e0 = expf(v0 - mx), e1 = expf(v1 - mx);
    float s = e0 + e1;
#pragma unroll
    for (int off = 1; off < 64; off <<= 1) s += __shfl_xor(s, off);
    float a0 = e0 / s, a1 = e1 / s;

    // (d) attn -> wave-private LDS
    if (act) {
      sattnH[qq0 * 28 + ii0] = a0;
      sattnH[(qq0 + 2) * 28 + ii0] = a1;
    }
    WSYNC();

    // (e) heads: lane (dp,qg) accumulates its 25 rows
    {
      const float* ap = sattnH + qg * 28;
      float ha = 0.f, hb = 0.f;
#pragma unroll
      for (int ii = 0; ii < 6; ++ii) {
        float4 v = ((const float4*)ap)[ii];
        ha = fmaf(v.x, gvt[4 * ii + 0], ha);
        hb = fmaf(v.y, gvt[4 * ii + 1], hb);
        ha = fmaf(v.z, gvt[4 * ii + 2], ha);
        hb = fmaf(v.w, gvt[4 * ii + 3], hb);
      }
      ha = fmaf(ap[24], gvt[24], ha);
      float hacc = ha + hb;
      hacc += __shfl_xor(hacc, 16);
      hacc += __shfl_xor(hacc, 32);
      if (l < 16) sheadsH[l] = hacc;
    }
    WSYNC();

    // (f) logits partial for my rows over this wave's 16 d
    float p0a = 0.f, p0b = 0.f, p1a = 0.f, p1b = 0.f;
#pragma unroll
    for (int jj = 0; jj < 2; ++jj) {
      float4 v = *(const float4*)&sheadsH[jj * 4];
      p0a = fmaf(v.x, lk0[4 * jj + 0], p0a); p1a = fmaf(v.x, lk1[4 * jj + 0], p1a);
      p0a = fmaf(v.y, lk0[4 * jj + 1], p0a); p1a = fmaf(v.y, lk1[4 * jj + 1], p1a);
      p0a = fmaf(v.z, lk0[4 * jj + 2], p0a); p1a = fmaf(v.z, lk1[4 * jj + 2], p1a);
      p0a = fmaf(v.w, lk0[4 * jj + 3], p0a); p1a = fmaf(v.w, lk1[4 * jj + 3], p1a);
    }
#pragma unroll
    for (int jj = 2; jj < 4; ++jj) {
      float4 v = *(const float4*)&sheadsH[jj * 4];
      p0b = fmaf(v.x, lk0[4 * jj + 0], p0b); p1b = fmaf(v.x, lk1[4 * jj + 0], p1b);
      p0b = fmaf(v.y, lk0[4 * jj + 1], p0b); p1b = fmaf(v.y, lk1[4 * jj + 1], p1b);
      p0b = fmaf(v.z, lk0[4 * jj + 2], p0b); p1b = fmaf(v.z, lk1[4 * jj + 2], p1b);
      p0b = fmaf(v.w, lk0[4 * jj + 3], p0b); p1b = fmaf(v.w, lk1[4 * jj + 3], p1b);
    }
    if (act) {
      spartB[par * 800 + h * 100 + r0] = p0a + p0b;
      spartB[par * 800 + h * 100 + r1] = p1a + p1b;
    }
    __syncthreads();  // THE barrier

    // (g) final logits: pairwise sum of 8 wave-partials, tanh-clip, mask
    const float* sp = spartB + par * 800;
    float t00 = sp[0 * 100 + r0] + sp[1 * 100 + r0];
    float t01 = sp[2 * 100 + r0] + sp[3 * 100 + r0];
    float t02 = sp[4 * 100 + r0] + sp[5 * 100 + r0];
    float t03 = sp[6 * 100 + r0] + sp[7 * 100 + r0];
    float u00 = sp[0 * 100 + r1] + sp[1 * 100 + r1];
    float u01 = sp[2 * 100 + r1] + sp[3 * 100 + r1];
    float u02 = sp[4 * 100 + r1] + sp[5 * 100 + r1];
    float u03 = sp[6 * 100 + r1] + sp[7 * 100 + r1];
    float s0 = (t00 + t01) + (t02 + t03);
    float s1 = (u00 + u01) + (u02 + u03);
    float l0 = (act && !m0f) ? 10.0f * tanhf(s0) : NEG_INF;
    float l1 = (act && !m1f) ? 10.0f * tanhf(s1) : NEG_INF;

    // (h) argmax butterfly || direct log-sum-exp (logits <= 10, so Z = sum e^l
    //     is safe: Z <= 100*e^10 ~ 2.2e6; masked e^-1e9 = 0). The two 6-level
    //     butterflies are independent -> ILP instead of serialization.
    float bv; int bi;
    if (l1 > l0) { bv = l1; bi = r1; } else { bv = l0; bi = act ? r0 : 1000; }
    float z = expf(l0) + expf(l1);
#pragma unroll
    for (int off = 1; off < 64; off <<= 1) {
      float ov = __shfl_xor(bv, off);
      int oi = __shfl_xor(bi, off);
      z += __shfl_xor(z, off);
      if (ov > bv || (ov == bv && oi < bi)) { bv = ov; bi = oi; }
    }
    const int sel = bi;  // identical in every lane
    float lsum = logf(z);

    // (i) outputs (wave 0 only)
    if (h == 0) {
      if (l == 0) out_pi[b * 100 + t] = (float)sel;
      if (act) {
        out_logp[lpbase + (size_t)t * 100 + r0] = l0 - lsum;
        out_logp[lpbase + (size_t)t * 100 + r1] = l1 - lsum;
      }
    }

    // (j) t==0: fold F = 0.25*emb[first]@W_step_top into ALL sE rows + done
    if (t == 0) {
      float fa = 0.f;
      for (int i = 0; i < 32; ++i) {
        int e = qg * 32 + i;
        float ev = sembf[sel * 128 + (((e >> 2) ^ (sel & 7)) << 2) + (e & 3)];
        fa = fmaf(ev, W_step[(size_t)e * 128 + h * 16 + dp], fa);
      }
      fa += __shfl_xor(fa, 16);
      fa += __shfl_xor(fa, 32);
      if (l < 16) sbase[h][l] = 0.25f * fa;
      WSYNC();
      if (act) {
        float4* p0 = (float4*)&sE[h][r0][0];
        float4* p1 = (float4*)&sE[h][r1][0];
#pragma unroll
        for (int jj = 0; jj < 4; ++jj) {
          float4 f = *(const float4*)&sbase[h][jj * 4];
          float4 c0 = p0[jj], c1 = p1[jj];
          c0.x += f.x; c0.y += f.y; c0.z += f.z; c0.w += f.w;
          c1.x += f.x; c1.y += f.y; c1.z += f.z; c1.w += f.w;
          p0[jj] = c0; p1[jj] = c1;
        }
      }
      WSYNC();
    }

    // (k) mask update + carry
    m0f = m0f || (act && sel == r0);
    m1f = m1f || (act && sel == r1);
    last = sel;
    par ^= 1;
  }
}

extern "C" void kernel_launch(void* const* d_in, const int* in_sizes, int n_in,
                              void* d_out, int out_size, void* d_ws, size_t ws_size,
                              hipStream_t stream) {
  const float* emb     = (const float*)d_in[0];
  const float* W_node  = (const float*)d_in[1];
  const float* W_fixed = (const float*)d_in[2];
  const float* W_step  = (const float*)d_in[3];
  const float* W_out   = (const float*)d_in[4];
  const float* W_ph    = (const float*)d_in[5];
  float* ws  = (float*)d_ws;
  float* out = (float*)d_out;

  hipLaunchKernelGGL(pre_kernel, dim3(65), dim3(128), 0, stream,
                     W_node, W_out, W_step, W_ph, ws);
  hipLaunchKernelGGL(decode_kernel, dim3(2048), dim3(512), 0, stream,
                     emb, W_node, W_fixed, W_step, ws, out, out + 20480000);
}